// Round 9
// baseline (437.826 us; speedup 1.0000x reference)
//
#include <hip/hip_runtime.h>

typedef unsigned short u16;
typedef __bf16 bf16x8 __attribute__((ext_vector_type(8)));
typedef u16 u16x8 __attribute__((ext_vector_type(8)));
typedef u16 u16x2 __attribute__((ext_vector_type(2)));
typedef float f32x4 __attribute__((ext_vector_type(4)));
typedef float f32x2 __attribute__((ext_vector_type(2)));

#define BSZ_ 2
#define NQ_ 128
#define LSEQ_ 2048
#define DM_ 256
#define DI_ 512
#define NH_ 8
#define HD_ 64
#define DKEY_ 1034
#define DCV_ 514
#define NCHUNK_ 16
#define CT_ 128   // chunk length

__device__ __forceinline__ float bf2f(u16 u) {
  unsigned v = ((unsigned)u) << 16;
  return __builtin_bit_cast(float, v);
}
__device__ __forceinline__ u16 f2bf(float f) {
  unsigned u = __builtin_bit_cast(unsigned, f);
  u += 0x7fffu + ((u >> 16) & 1u);
  return (u16)(u >> 16);
}
__device__ __forceinline__ float sigmoidf_(float x) { return 1.f / (1.f + expf(-x)); }
__device__ __forceinline__ float softplusf_(float x) {
  return (x > 20.f) ? x : log1pf(expf(x));
}

template<bool F32>
__device__ __forceinline__ float ldi(const void* p, size_t i) {
  return F32 ? ((const float*)p)[i] : bf2f(((const u16*)p)[i]);
}
template<bool F32>
__device__ __forceinline__ void sto(void* p, size_t i, float v) {
  if (F32) ((float*)p)[i] = v;
  else ((u16*)p)[i] = f2bf(v);
}

// per-wave dtype detection (all waves read same 64 u16s -> uniform result)
__device__ __forceinline__ bool detect_f32(const void* feat) {
  int lane = threadIdx.x & 63;
  float a = fabsf(bf2f(((const u16*)feat)[2*lane]));
  bool plaus = (a > 1e-6f) && (a < 1e6f);
  unsigned long long m = __ballot(plaus);
  return __popcll(m) < 32;   // true => fp32 storage
}

// ---------------- workspace layout (float units) ----------------
constexpr size_t SZ_KP    = (size_t)BSZ_*LSEQ_*DKEY_;
constexpr size_t SZ_XACT  = (size_t)BSZ_*LSEQ_*DCV_;
constexpr size_t SZ_AW    = (size_t)BSZ_*NH_*LSEQ_*NQ_*2;
constexpr size_t SZ_CARR  = (size_t)BSZ_*LSEQ_*NQ_;
constexpr size_t SZ_QPROJ = (size_t)BSZ_*NQ_*DI_;
constexpr size_t SZ_YACC  = (size_t)BSZ_*LSEQ_*DI_;
constexpr size_t SZ_SEND  = (size_t)BSZ_*NH_*2*NCHUNK_*NQ_*HD_;
constexpr size_t SZ_PTOT  = (size_t)BSZ_*NH_*2*NCHUNK_*NQ_;
constexpr size_t SZ_H0    = SZ_SEND;
constexpr size_t SZ_HB    = (size_t)BSZ_*NH_*2*NQ_*HD_;
constexpr size_t SZ_GBUF  = (size_t)BSZ_*LSEQ_*DI_/2;
constexpr size_t SZ_OUTQF = (size_t)BSZ_*NQ_*DM_;
constexpr size_t SZ_WPREP = 2048;

constexpr size_t OFF_KP    = 0;
constexpr size_t OFF_XACT  = OFF_KP + SZ_KP;
constexpr size_t OFF_AW    = OFF_XACT + SZ_XACT;
constexpr size_t OFF_CARR  = OFF_AW + SZ_AW;
constexpr size_t OFF_QPROJ = OFF_CARR + SZ_CARR;
constexpr size_t OFF_YACC  = OFF_QPROJ + SZ_QPROJ;
constexpr size_t OFF_SEND  = OFF_YACC + SZ_YACC;
constexpr size_t OFF_PTOT  = OFF_SEND + SZ_SEND;
constexpr size_t OFF_H0    = OFF_PTOT + SZ_PTOT;
constexpr size_t OFF_HB    = OFF_H0 + SZ_H0;
constexpr size_t OFF_GBUF  = OFF_HB + SZ_HB;
constexpr size_t OFF_OUTQF = OFF_GBUF + SZ_GBUF;
constexpr size_t OFF_WPREP = OFF_OUTQF + SZ_OUTQF;
constexpr size_t WS_FLOATS = OFF_WPREP + SZ_WPREP;

// FFN/outq scratch aliases into AW (dead after s3):
constexpr size_t OFF_UG  = OFF_AW;                         // 256x1024 bf16
constexpr size_t OFF_LNQ = OFF_UG + (size_t)256*1024/2;    // 256x512 bf16

// Transient bf16 cast buffers alias SEND (dead until s1 writes it):
constexpr size_t OFF_ABUF = OFF_SEND;                         // 4096x256 bf16
constexpr size_t OFF_AQ   = OFF_ABUF + (size_t)4096*256/2;
constexpr size_t OFF_BKEY = OFF_AQ + (size_t)256*256/2;
constexpr size_t OFF_BQ   = OFF_BKEY + (size_t)(256*1034+1)/2 + 1;
// Late bf16 weight casts alias SEND (dead after s2):
constexpr size_t OFF_BOK  = OFF_SEND;
constexpr size_t OFF_BOQ  = OFF_BOK + (size_t)512*256/2;
constexpr size_t OFF_B1W  = OFF_BOQ + (size_t)512*256/2;
constexpr size_t OFF_B2W  = OFF_B1W + (size_t)256*2048/2;

// wprep layout: [0..7] A=-exp(A_log); [8..15] dt_bias; [32..287] w1b; [288..1311] w2;
// [1312..1343] bc_proj; [1344..1471] dt_proj
template<bool F32>
__device__ void prep_body(const void* A_log, const void* dt_bias,
                          const void* w1, const void* b1, const void* w2,
                          const void* bcw, const void* dtw, float* wp) {
  int t = threadIdx.x;
  if (t < 8) {
    wp[t]     = -expf(ldi<F32>(A_log, t));
    wp[8 + t] = ldi<F32>(dt_bias, t);
  }
  if (t < 64) {
    wp[32 + t*4 + 0] = ldi<F32>(w1, 0*64 + t);
    wp[32 + t*4 + 1] = ldi<F32>(w1, 1*64 + t);
    wp[32 + t*4 + 2] = ldi<F32>(w1, 2*64 + t);
    wp[32 + t*4 + 3] = ldi<F32>(b1, t);
  }
  for (int i = t; i < 1024; i += 256) wp[288 + i] = ldi<F32>(w2, i);
  if (t < 32)  wp[1312 + t] = ldi<F32>(bcw, t);
  if (t < 128) wp[1344 + t] = ldi<F32>(dtw, t);
}

// cast helper: d[i] = bf16(s0[i] (+ s1_[i]))
__device__ __forceinline__ void cast_job(bool F32, const void* s0, const void* s1_,
                                         u16* d, size_t n, size_t base, size_t stride) {
  for (size_t i = base; i < n; i += stride) {
    float v = F32 ? ((const float*)s0)[i] : bf2f(((const u16*)s0)[i]);
    if (s1_) v += F32 ? ((const float*)s1_)[i] : bf2f(((const u16*)s1_)[i]);
    d[i] = f2bf(v);
  }
}

// ---------------- setup: yacc zero + cast0 + detect/prep (fused) ----------------
__global__ __launch_bounds__(256) void setup_kernel(
    const void* feat, const void* pe, u16* abuf,
    const void* q, const void* qp, u16* aq,
    const void* kw, u16* bkey, const void* qw, u16* bq,
    const void* A_log, const void* dt_bias, const void* w1, const void* b1,
    const void* w2, const void* bcw, const void* dtw, float* wp,
    float* yacc, int* flag)
{
  int bx = blockIdx.x, tid = threadIdx.x;
  if (bx < 512) {                       // yacc zero: 512 blocks x 4096 floats
    size_t base = (size_t)bx * 4096 + tid;
#pragma unroll
    for (int k = 0; k < 16; ++k) yacc[base + (size_t)k*256] = 0.f;
    return;
  }
  bool F32 = detect_f32(feat);
  if (bx < 1024) {                      // abuf = bf16(features + pos_embed)
    cast_job(F32, feat, pe, abuf, (size_t)4096*256,
             (size_t)(bx-512)*256 + tid, (size_t)512*256);
  } else if (bx < 1056) {               // aq = bf16(queries + query_pos)
    cast_job(F32, q, qp, aq, (size_t)256*256,
             (size_t)(bx-1024)*256 + tid, (size_t)32*256);
  } else if (bx < 1184) {               // bkey = bf16(key_proj_w)
    cast_job(F32, kw, nullptr, bkey, (size_t)256*1034,
             (size_t)(bx-1056)*256 + tid, (size_t)128*256);
  } else if (bx < 1248) {               // bq = bf16(query_proj_w)
    cast_job(F32, qw, nullptr, bq, (size_t)256*512,
             (size_t)(bx-1184)*256 + tid, (size_t)64*256);
  } else {                              // detect-store + prep
    if (tid == 0) *flag = F32 ? 1 : 0;
    if (F32) prep_body<true>(A_log, dt_bias, w1, b1, w2, bcw, dtw, wp);
    else     prep_body<false>(A_log, dt_bias, w1, b1, w2, bcw, dtw, wp);
  }
}

// ---------------- MFMA GEMM body (Bs padded to 42: bank-conflict-free) ----------
// BV: B-stage vector width. 2 = unconditional u16x8 (row stride 16B-aligned,
// tiles always full: N in {256,512}); 1 = guarded 4x u16x2 (4B-aligned only,
// N=1034); 0 = scalar fallback. The old per-element bounds check defeated load
// merging -> 8 scalar global_load_ushort per thread per k-iter.
template<int A_MODE, int B_MODE, int BV, int OUT_EXT, int RES_EXT, int RES_F32, int BIAS, bool F32>
__device__ void gemm_body(int bm, int bn,
                          const void* A0, const void* A1, const void* Bw,
                          float* Cf, void* Cext, const void* ResE,
                          const float* ResF, const void* Bias,
                          int M, int N, int K) {
  __shared__ u16 As[64][40];
  __shared__ u16 Bs[64][42];
  int tid = threadIdx.x;
  int w = tid >> 6, lane = tid & 63;
  f32x4 acc[4];
#pragma unroll
  for (int j = 0; j < 4; ++j) acc[j] = (f32x4){0.f, 0.f, 0.f, 0.f};

  int arow = tid >> 2, aseg = (tid & 3) * 8;
  int bkl = tid >> 3, bns = (tid & 7) * 8;

  for (int k0 = 0; k0 < K; k0 += 32) {
    {
      size_t abase = (size_t)(bm + arow) * K + k0 + aseg;
      u16x8 tv;
      if (A_MODE == 0) {
#pragma unroll
        for (int i = 0; i < 8; ++i)
          tv[i] = f2bf(ldi<F32>(A0, abase + i) + ldi<F32>(A1, abase + i));
      } else {
        tv = *(const u16x8*)((const u16*)A0 + abase);   // 16B-aligned for all uses
      }
      *(u16x8*)&As[arow][aseg] = tv;
    }
    {
      size_t bbase = (size_t)(k0 + bkl) * N + bn + bns;
      if (BV == 2) {
        u16x8 bv8 = *(const u16x8*)((const u16*)Bw + bbase);
#pragma unroll
        for (int i = 0; i < 8; ++i) Bs[bns + i][bkl] = bv8[i];
      } else if (BV == 1 && bn + bns + 8 <= N) {
        const u16* bp = (const u16*)Bw + bbase;
#pragma unroll
        for (int i2 = 0; i2 < 4; ++i2) {
          u16x2 v2 = *(const u16x2*)(bp + i2*2);
          Bs[bns + i2*2][bkl]     = v2[0];
          Bs[bns + i2*2 + 1][bkl] = v2[1];
        }
      } else {
#pragma unroll
        for (int i = 0; i < 8; ++i) {
          u16 v;
          if (bn + bns + i < N) {
            if (B_MODE == 1) v = ((const u16*)Bw)[bbase + i];
            else             v = f2bf(ldi<F32>(Bw, bbase + i));
          } else v = (u16)0;
          Bs[bns + i][bkl] = v;
        }
      }
    }
    __syncthreads();
    int mrow = w * 16 + (lane & 15);
    int kq = (lane >> 4) * 8;
    bf16x8 af = __builtin_bit_cast(bf16x8, *(const u16x8*)&As[mrow][kq]);
#pragma unroll
    for (int j = 0; j < 4; ++j) {
      bf16x8 bfv = __builtin_bit_cast(bf16x8, *(const u16x8*)&Bs[j*16 + (lane & 15)][kq]);
      acc[j] = __builtin_amdgcn_mfma_f32_16x16x32_bf16(af, bfv, acc[j], 0, 0, 0);
    }
    __syncthreads();
  }
  int col0 = lane & 15, rbase = (lane >> 4) * 4;
#pragma unroll
  for (int j = 0; j < 4; ++j) {
#pragma unroll
    for (int r = 0; r < 4; ++r) {
      int row = bm + w * 16 + rbase + r;
      int col = bn + j * 16 + col0;
      if (col < N) {
        size_t idx = (size_t)row * N + col;
        float v = acc[j][r];
        if (BIAS)    v += ldi<F32>(Bias, col);
        if (RES_EXT) v += ldi<F32>(ResE, idx);
        if (RES_F32) v += ResF[idx];
        if (OUT_EXT) sto<F32>(Cext, idx, v);
        else         Cf[idx] = v;
      }
    }
  }
}

// kp = abuf @ bkey (all-internal bf16, fp32 out); N=1034 -> BV=1 (4B-aligned)
__global__ __launch_bounds__(256) void kp_gemm_kernel(
    const u16* abuf, const u16* bkey, float* kp) {
  gemm_body<1,1,1,0,0,0,0,false>(blockIdx.x*64, blockIdx.y*64, abuf, nullptr, bkey,
                                 kp, nullptr, nullptr, nullptr, nullptr,
                                 4096, DKEY_, DM_);
}

// fc2: out_q = outqf + ug @ b2w + b2
template<bool F32>
__device__ void fc2_body(const u16* ug, const u16* b2w, void* out_q,
                         const float* outqf, const void* b2) {
  gemm_body<1,1,2,1,0,1,1,F32>((blockIdx.x&3)*64, (blockIdx.x>>2)*64, ug, nullptr,
                               b2w, nullptr, out_q, nullptr, outqf, b2,
                               BSZ_*NQ_, DM_, 1024);
}
__global__ __launch_bounds__(256) void fc2_kernel(
    const int* fl, const u16* ug, const u16* b2w, void* out_q,
    const float* outqf, const void* b2) {
  if (*fl) fc2_body<true>(ug, b2w, out_q, outqf, b2);
  else     fc2_body<false>(ug, b2w, out_q, outqf, b2);
}

// ---------------- conv body (row passed in) ----------------
template<bool F32>
__device__ void conv_body(const float* kp, const void* cw, const void* cb,
                          float* xact, int row) {
  int l = row & (LSEQ_ - 1);
  for (int ch = threadIdx.x; ch < DCV_; ch += 256) {
    float acc = ldi<F32>(cb, ch);
#pragma unroll
    for (int k = 0; k < 4; ++k) {
      int ll = l - 3 + k;
      if (ll >= 0)
        acc = fmaf(ldi<F32>(cw, ch*4 + k), kp[(size_t)(row - 3 + k)*DKEY_ + DI_ + ch], acc);
    }
    xact[(size_t)row*DCV_ + ch] = acc * sigmoidf_(acc);
  }
}

// ---------------- dist MLP -> a, w, c (xact dependency removed) ----------------
// bb_/cb_ (conv channels 512/513) are recomputed locally from kp: 8 FMA + 2
// silu per row -- removes the conv->dist launch dependency so conv, qproj and
// dist run as independent block ranges of ONE kernel.
template<bool F32>
__device__ void dist_body(const void* anchors, const void* key_pos,
                          const float* kp, const void* cw, const void* cb,
                          const float* wp, float* aw, float* carr) {
  int tid = threadIdx.x;
  int n = tid & 127;
  int idx = blockIdx.x;
  int b = idx >> 10;
  int l = ((idx & 1023) << 1) | (tid >> 7);
  size_t row = (size_t)b * LSEQ_ + l;

  float enc0, enc1, enc2;
  {
    float e[3];
#pragma unroll
    for (int d = 0; d < 3; ++d) {
      float delta = ldi<F32>(anchors, (b*NQ_ + n)*3 + d) - ldi<F32>(key_pos, row*3 + d);
      float s = delta < 0.f ? -1.f : 1.f;
      e[d] = s * log2f(fabsf(delta) * 20.f + 1.f) * (1.f/12.f);
    }
    enc0 = e[0]; enc1 = e[1]; enc2 = e[2];
  }
  // recompute conv channels 512/513 (b_bias, c_bias) from kp
  float acc0 = ldi<F32>(cb, 512);
  float acc1 = ldi<F32>(cb, 513);
#pragma unroll
  for (int k = 0; k < 4; ++k) {
    int ll = l - 3 + k;
    if (ll >= 0) {
      acc0 = fmaf(ldi<F32>(cw, 512*4 + k), kp[(row - 3 + k)*DKEY_ + DI_ + 512], acc0);
      acc1 = fmaf(ldi<F32>(cw, 513*4 + k), kp[(row - 3 + k)*DKEY_ + DI_ + 513], acc1);
    }
  }
  float bb_ = acc0 * sigmoidf_(acc0);
  float cb_ = acc1 * sigmoidf_(acc1);

  float feat[16];
#pragma unroll
  for (int f = 0; f < 16; ++f) feat[f] = 0.f;
  for (int j = 0; j < 64; ++j) {
    float w0 = wp[32 + j*4], w1v = wp[33 + j*4], w2v = wp[34 + j*4], bb = wp[35 + j*4];
    float hj = fmaxf(fmaf(enc0, w0, fmaf(enc1, w1v, fmaf(enc2, w2v, bb))), 0.f);
#pragma unroll
    for (int f = 0; f < 16; ++f) feat[f] = fmaf(hj, wp[288 + j*16 + f], feat[f]);
  }
  float bc0 = 0.f, bc1 = 0.f;
#pragma unroll
  for (int f = 0; f < 16; ++f) {
    bc0 = fmaf(feat[f], wp[1312 + f*2], bc0);
    bc1 = fmaf(feat[f], wp[1313 + f*2], bc1);
  }
  float Bs = bc0 + bb_, Cs = bc1 + cb_;
  carr[row*NQ_ + n] = Cs;

  float dtb[8];
#pragma unroll
  for (int h = 0; h < 8; ++h) dtb[h] = 0.f;
#pragma unroll
  for (int f = 0; f < 16; ++f)
#pragma unroll
    for (int h = 0; h < 8; ++h) dtb[h] = fmaf(feat[f], wp[1344 + f*8 + h], dtb[h]);

#pragma unroll
  for (int h = 0; h < 8; ++h) {
    float xln = dtb[h] + kp[row*DKEY_ + (DI_*2 + 2) + h] + wp[8 + h];
    float dtv = softplusf_(xln);
    float a = expf(dtv * wp[h]);
    float wv = dtv * Bs;
    size_t o = (((size_t)(b*NH_ + h)*LSEQ_ + l)*NQ_ + n)*2;
    aw[o] = a;
    aw[o + 1] = wv;
  }
}

// ---------------- merged: dist + conv + qproj GEMM (one launch) ----------------
__global__ __launch_bounds__(256) void cdq_kernel(
    const int* fl, const float* kp, const void* cw, const void* cb, float* xact,
    const u16* aq, const u16* bq, float* qproj,
    const void* anchors, const void* key_pos, const float* wp,
    float* aw, float* carr)
{
  int bx = blockIdx.x;
  if (bx < 2048) {            // dist
    if (*fl) dist_body<true>(anchors, key_pos, kp, cw, cb, wp, aw, carr);
    else     dist_body<false>(anchors, key_pos, kp, cw, cb, wp, aw, carr);
  } else if (bx < 6144) {     // conv
    if (*fl) conv_body<true>(kp, cw, cb, xact, bx - 2048);
    else     conv_body<false>(kp, cw, cb, xact, bx - 2048);
  } else {                    // qproj: 32 blocks, M=256 (4) x N=512 (8), K=256
    int i = bx - 6144;
    gemm_body<1,1,2,0,0,0,0,false>((i&3)*64, (i>>2)*64, aq, nullptr, bq,
                                   qproj, nullptr, nullptr, nullptr, nullptr,
                                   BSZ_*NQ_, DI_, DM_);
  }
}

// ---------------- scan phase 1: group-LDS-staged ----------------
__global__ __launch_bounds__(256) void s1m_kernel(
    const float* __restrict__ aw, const float* __restrict__ xact,
    float* __restrict__ send, float* __restrict__ ptot)
{
  __shared__ float awl[2][8][32];   // 2 KB: 16 n x 2 floats per step
  __shared__ float xl [2][8][64];   // 4 KB
  int tid = threadIdx.x;
  int hd = tid & 63;
  int w = __builtin_amdgcn_readfirstlane(tid >> 6);
  int ns = blockIdx.x, q = blockIdx.y, z = blockIdx.z;   // z = b*NH_ + h
  int h = z & 7, b = z >> 3;
  int n0 = __builtin_amdgcn_readfirstlane(ns*16 + w*4);

  float hf[4], hb[4], pr[4];
#pragma unroll
  for (int i = 0; i < 4; ++i) { hf[i] = 0.f; hb[i] = 0.f; pr[i] = 1.f; }

  // stage thread mapping: s8 = step-in-group (0..7), j = 0..31
  int s8 = tid >> 5, j = tid & 31;
  int t0 = q*CT_;
  const float* awg = aw + (size_t)z*LSEQ_*(NQ_*2)
                     + (size_t)(t0 + s8)*(NQ_*2) + ns*32 + j;
  const float* xg  = xact + ((size_t)(b*LSEQ_) + t0 + s8)*DCV_ + (h<<6) + j*2;
  const long awgstep = 8L*(NQ_*2);
  const long xgstep  = 8L*DCV_;

  // prologue: stage group 0
  {
    float pa = *awg;
    f32x2 px = *(const f32x2*)xg;
    awg += awgstep; xg += xgstep;
    awl[0][s8][j] = pa;
    *(f32x2*)&xl[0][s8][j*2] = px;
  }
  asm volatile("s_waitcnt lgkmcnt(0)" ::: "memory");
  __builtin_amdgcn_s_barrier();

  int p = 0;
  float sa; f32x2 sx;
  for (int g = 0; g < 16; ++g) {
    if (g < 15) {
      sa = *awg; sx = *(const f32x2*)xg;
      awg += awgstep; xg += xgstep;
    }
#pragma unroll
    for (int s = 0; s < 8; ++s) {
      const float* A = &awl[p][s][w*8];
      float xv = xl[p][s][hd];
#pragma unroll
      for (int i = 0; i < 4; ++i) {
        float a = A[2*i], wv = A[2*i + 1];
        float wx = wv * xv;
        hf[i] = fmaf(hf[i], a, wx);
        hb[i] = fmaf(pr[i], wx, hb[i]);
        pr[i] *= a;
      }
    }
    if (g < 15) {
      awl[p^1][s8][j] = sa;
      *(f32x2*)&xl[p^1][s8][j*2] = sx;
    }
    asm volatile("s_waitcnt lgkmcnt(0)" ::: "memory");
    __builtin_amdgcn_s_barrier();
    p ^= 1;
  }

  size_t cbf = (size_t)((z*2 + 0)*NCHUNK_ + q);
  size_t cbb = (size_t)((z*2 + 1)*NCHUNK_ + (NCHUNK_ - 1 - q));
#pragma unroll
  for (int i = 0; i < 4; ++i) {
    send[cbf*(NQ_*HD_) + (size_t)(n0 + i)*HD_ + hd] = hf[i];
    send[cbb*(NQ_*HD_) + (size_t)(n0 + i)*HD_ + hd] = hb[i];
  }
  if (hd == 0) {
#pragma unroll
    for (int i = 0; i < 4; ++i) {
      ptot[cbf*NQ_ + n0 + i] = pr[i];
      ptot[cbb*NQ_ + n0 + i] = pr[i];
    }
  }
}

// ---------------- scan phase 2 ----------------
__global__ __launch_bounds__(256) void s2_kernel(
    const float* __restrict__ qproj, const float* __restrict__ ptot,
    const float* __restrict__ send, float* __restrict__ h0buf,
    float* __restrict__ hbuf)
{
  int g = blockIdx.x*256 + threadIdx.x;
  int hd = g & 63;
  int n = (g >> 6) & 127;
  int dir = (g >> 13) & 1;
  int h = (g >> 14) & 7;
  int b = g >> 17;
  float hcur = qproj[((size_t)(b*NQ_ + n))*DI_ + h*HD_ + hd];
  size_t base = (size_t)((b*NH_ + h)*2 + dir) * NCHUNK_;
  for (int q = 0; q < NCHUNK_; ++q) {
    size_t cb = base + q;
    h0buf[cb*(NQ_*HD_) + (size_t)n*HD_ + hd] = hcur;
    hcur = fmaf(hcur, ptot[cb*NQ_ + n], send[cb*(NQ_*HD_) + (size_t)n*HD_ + hd]);
  }
  hbuf[((size_t)((b*NH_ + h)*2 + dir))*(NQ_*HD_) + (size_t)n*HD_ + hd] = hcur;
}

// ---------------- scan phase 3: group-LDS-staged (r6, PROVEN ~87us) ------------
// Unchanged — serves as the control for this round's changes.
template<bool F32>
__device__ void cast1_part(const void* okw, u16* bok, const void* oqw, u16* boq,
                           const void* w1, u16* b1w, const void* w2, u16* b2w) {
  int i = blockIdx.x - 2048;
  int job = i >> 7, bj = i & 127;
  size_t base = (size_t)bj*256 + threadIdx.x, stride = (size_t)128*256;
  switch (job) {
    case 0: cast_job(F32, okw, nullptr, bok, (size_t)512*256, base, stride); break;
    case 1: cast_job(F32, oqw, nullptr, boq, (size_t)512*256, base, stride); break;
    case 2: cast_job(F32, w1, nullptr, b1w, (size_t)256*2048, base, stride); break;
    default: cast_job(F32, w2, nullptr, b2w, (size_t)1024*256, base, stride); break;
  }
}
__global__ __launch_bounds__(256) void s3cast_kernel(
    const int* fl, const float* __restrict__ aw, const float* __restrict__ carr,
    const float* __restrict__ xact, const float* __restrict__ h0buf,
    float* __restrict__ yacc,
    const void* okw, u16* bok, const void* oqw, u16* boq,
    const void* w1, u16* b1w, const void* w2, u16* b2w)
{
  int bx = blockIdx.x;
  if (bx >= 2048) {
    if (*fl) cast1_part<true>(okw, bok, oqw, boq, w1, b1w, w2, b2w);
    else     cast1_part<false>(okw, bok, oqw, boq, w1, b1w, w2, b2w);
    return;
  }
  __shared__ float awl[2][8][64];   // 4 KB
  __shared__ float ctl[2][8][32];   // 2 KB
  __shared__ float xl [2][8][64];   // 4 KB
  __shared__ float yl [8][4][64];   // 8 KB

  int tid = threadIdx.x;
  int hd = tid & 63;
  int w = __builtin_amdgcn_readfirstlane(tid >> 6);
  int ns = bx & 3, q = (bx >> 2) & 15, zz = bx >> 6;
  int dir = zz & 1, h = (zz >> 1) & 7, b = zz >> 4;
  int z = b*NH_ + h;
  int n0 = ns*32 + w*8;

  int tbase = dir ? (LSEQ_ - 1 - q*CT_) : (q*CT_);
  int tstep = dir ? -1 : 1;

  // stage thread mapping: s8 = step-in-group, j = 0..31
  int s8 = tid >> 5, j = tid & 31;
  const float* awg = aw + (size_t)z*LSEQ_*(NQ_*2)
                     + (size_t)(tbase + tstep*s8)*(NQ_*2) + ns*64 + j*2;
  const float* ctg = carr + ((size_t)(b*LSEQ_) + tbase + tstep*s8)*NQ_ + ns*32 + j;
  const float* xg  = xact + ((size_t)(b*LSEQ_) + tbase + tstep*s8)*DCV_ + (h<<6) + j*2;
  long awgstep = (long)tstep*8*(NQ_*2);
  long ctgstep = (long)tstep*8*NQ_;
  long xgstep  = (long)tstep*8*DCV_;

  // prologue: issue stage(group 0) loads first (deep), then h0 state loads
  f32x2 pa = *(const f32x2*)awg;
  float pc = *ctg;
  f32x2 px = *(const f32x2*)xg;
  awg += awgstep; ctg += ctgstep; xg += xgstep;

  float h0_, h1_, h2_, h3_, h4_, h5_, h6_, h7_;
  {
    size_t cb = (size_t)((z*2 + dir)*NCHUNK_ + q);
    const float* hp = h0buf + cb*(NQ_*HD_) + (size_t)n0*HD_ + hd;
    h0_ = hp[0*HD_]; h1_ = hp[1*HD_]; h2_ = hp[2*HD_]; h3_ = hp[3*HD_];
    h4_ = hp[4*HD_]; h5_ = hp[5*HD_]; h6_ = hp[6*HD_]; h7_ = hp[7*HD_];
  }
  *(f32x2*)&awl[0][s8][j*2] = pa;
  ctl[0][s8][j] = pc;
  *(f32x2*)&xl[0][s8][j*2] = px;
  asm volatile("s_waitcnt lgkmcnt(0)" ::: "memory");
  __builtin_amdgcn_s_barrier();

  float* yrow = yacc + ((size_t)(b*LSEQ_) + tbase)*DI_ + (h << 6) + hd;
  long ystep = (long)tstep * DI_;

  int p = 0;
  f32x2 sa; float sc; f32x2 sx;
  for (int g = 0; g < 16; ++g) {
    if (g < 15) {
      sa = *(const f32x2*)awg; sc = *ctg; sx = *(const f32x2*)xg;
      awg += awgstep; ctg += ctgstep; xg += xgstep;
    }
    if (g > 0) {
#pragma unroll
      for (int r = 0; r < 2; ++r) {
        int s = w + r*4;
        float yv = yl[s][0][hd] + yl[s][1][hd] + yl[s][2][hd] + yl[s][3][hd];
        atomicAdd(yrow + (long)((g-1)*8 + s)*ystep, 0.5f * yv);
      }
    }
    asm volatile("s_waitcnt lgkmcnt(0)" ::: "memory");
    __builtin_amdgcn_s_barrier();           // yl reads done before overwrite
#pragma unroll
    for (int s = 0; s < 8; ++s) {
      const float* A = &awl[p][s][w*16];
      const float* C = &ctl[p][s][w*8];
      float xv = xl[p][s][hd];
      float ya, yb;
      h0_ = fmaf(h0_, A[0],  A[1]*xv);  ya = h0_ * C[0];
      h1_ = fmaf(h1_, A[2],  A[3]*xv);  yb = h1_ * C[1];
      h2_ = fmaf(h2_, A[4],  A[5]*xv);  ya = fmaf(h2_, C[2], ya);
      h3_ = fmaf(h3_, A[6],  A[7]*xv);  yb = fmaf(h3_, C[3], yb);
      h4_ = fmaf(h4_, A[8],  A[9]*xv);  ya = fmaf(h4_, C[4], ya);
      h5_ = fmaf(h5_, A[10], A[11]*xv); yb = fmaf(h5_, C[5], yb);
      h6_ = fmaf(h6_, A[12], A[13]*xv); ya = fmaf(h6_, C[6], ya);
      h7_ = fmaf(h7_, A[14], A[15]*xv); yb = fmaf(h7_, C[7], yb);
      yl[s][w][hd] = ya + yb;
    }
    if (g < 15) {
      *(f32x2*)&awl[p^1][s8][j*2] = sa;
      ctl[p^1][s8][j] = sc;
      *(f32x2*)&xl[p^1][s8][j*2] = sx;
    }
    asm volatile("s_waitcnt lgkmcnt(0)" ::: "memory");
    __builtin_amdgcn_s_barrier();           // staged buffer ready for g+1
    p ^= 1;
  }
#pragma unroll
  for (int r = 0; r < 2; ++r) {
    int s = w + r*4;
    float yv = yl[s][0][hd] + yl[s][1][hd] + yl[s][2][hd] + yl[s][3][hd];
    atomicAdd(yrow + (long)(15*8 + s)*ystep, 0.5f * yv);
  }
}

// ---------------- block reduction helper ----------------
__device__ __forceinline__ float block_sum256(float v, float* red) {
#pragma unroll
  for (int off = 32; off; off >>= 1) v += __shfl_xor(v, off, 64);
  int wv = threadIdx.x >> 6;
  if ((threadIdx.x & 63) == 0) red[wv] = v;
  __syncthreads();
  float t = red[0] + red[1] + red[2] + red[3];
  __syncthreads();
  return t;
}

// ---------------- g (gated RMSNorm) + lnq (fused) ----------------
template<bool F32>
__device__ void g_body(const float* yacc, const float* xact, const float* kp,
                       const void* Dv, const void* knw, u16* gbuf) {
  int row = blockIdx.x, tid = threadIdx.x;
  __shared__ float red[4];
  float gg[2];
  float ss = 0.f;
#pragma unroll
  for (int ii = 0; ii < 2; ++ii) {
    int ch = tid + ii*256;
    float yv = yacc[(size_t)row*DI_ + ch];
    float xv = xact[(size_t)row*DCV_ + ch];
    float zv = kp[(size_t)row*DKEY_ + ch];
    float Dh = ldi<F32>(Dv, ch >> 6);
    float yf = yv + 2.f * Dh * xv;
    float g = yf * (zv * sigmoidf_(zv));
    gg[ii] = g;
    ss += g * g;
  }
  float tot = block_sum256(ss, red);
  float r = rsqrtf(tot / (float)DI_ + 1e-5f);
#pragma unroll
  for (int ii = 0; ii < 2; ++ii) {
    int ch = tid + ii*256;
    gbuf[(size_t)row*DI_ + ch] = f2bf(gg[ii] * r * ldi<F32>(knw, ch));
  }
}
template<bool F32>
__device__ void lnq_body(const float* hbuf, const void* qnw, const void* qnb,
                         u16* lnq) {
  int row = blockIdx.x - 4096;
  int b = row >> 7, n = row & 127;
  int tid = threadIdx.x;
  __shared__ float red[4];
  float hv[2];
  float s1 = 0.f, s2 = 0.f;
#pragma unroll
  for (int ii = 0; ii < 2; ++ii) {
    int ch = tid + ii*256;
    int h = ch >> 6, hd = ch & 63;
    size_t base = ((size_t)((b*NH_ + h)*2))*(NQ_*HD_) + (size_t)n*HD_ + hd;
    float v = 0.5f * (hbuf[base] + hbuf[base + (size_t)NQ_*HD_]);
    hv[ii] = v;
    s1 += v;
    s2 += v * v;
  }
  s1 = block_sum256(s1, red);
  s2 = block_sum256(s2, red);
  float mean = s1 / (float)DI_;
  float var = fmaxf(s2 / (float)DI_ - mean * mean, 0.f);
  float rstd = rsqrtf(var + 1e-5f);
#pragma unroll
  for (int ii = 0; ii < 2; ++ii) {
    int ch = tid + ii*256;
    lnq[(size_t)row*DI_ + ch] =
        f2bf((hv[ii] - mean) * rstd * ldi<F32>(qnw, ch) + ldi<F32>(qnb, ch));
  }
}
__global__ __launch_bounds__(256) void glnq_kernel(
    const int* fl, const float* yacc, const float* xact, const float* kp,
    const void* Dv, const void* knw, u16* gbuf,
    const float* hbuf, const void* qnw, const void* qnb, u16* lnq)
{
  if (blockIdx.x < 4096) {
    if (*fl) g_body<true>(yacc, xact, kp, Dv, knw, gbuf);
    else     g_body<false>(yacc, xact, kp, Dv, knw, gbuf);
  } else {
    if (*fl) lnq_body<true>(hbuf, qnw, qnb, lnq);
    else     lnq_body<false>(hbuf, qnw, qnb, lnq);
  }
}

// ---------------- out_feat GEMM + outq GEMM (fused) ----------------
template<bool F32>
__device__ void ofoq_body(const u16* gbuf, const u16* bok, void* out_feat,
                          const void* features, const u16* lnq, const u16* boq,
                          float* outqf, const void* queries) {
  int bx = blockIdx.x;
  if (bx < 256) {   // out_feat: M=4096 (64 tiles) x N=256 (4 tiles), K=512
    gemm_body<1,1,2,1,1,0,0,F32>((bx>>2)*64, (bx&3)*64, gbuf, nullptr, bok,
                                 nullptr, out_feat, features, nullptr, nullptr,
                                 4096, DM_, DI_);
  } else {          // outq: M=256 (4) x N=256 (4), K=512
    int i = bx - 256;
    gemm_body<1,1,2,0,1,0,0,F32>((i&3)*64, (i>>2)*64, lnq, nullptr, boq,
                                 outqf, nullptr, queries, nullptr, nullptr,
                                 BSZ_*NQ_, DM_, DI_);
  }
}
__global__ __launch_bounds__(256) void ofoq_kernel(
    const int* fl, const u16* gbuf, const u16* bok,
    void* out_feat_f32, void* out_feat_bf16, const void* features,
    const u16* lnq, const u16* boq, float* outqf, const void* queries) {
  if (*fl) ofoq_body<true>(gbuf, bok, out_feat_f32, features, lnq, boq, outqf, queries);
  else     ofoq_body<false>(gbuf, bok, out_feat_bf16, features, lnq, boq, outqf, queries);
}

// ---------------- fc1 + gelu, with IN-BLOCK FFN LayerNorm (lnf kernel removed) --
// Each block LN-normalizes its 64 outqf rows (4 threads/row, f32, same math as
// the old lnf kernel modulo reduction order) into a persistent LDS tile
// Asf[64][264] (pad 264: 528B row stride -> 16B-aligned u16x8 reads, bank
// rotation 4/row). The k-loop reads A from Asf directly; only B is re-staged.
template<bool F32>
__device__ void fc1g_body(const float* outqf, const void* fnw, const void* fnb,
                          const u16* b1w, const void* b1, u16* ug) {
  __shared__ u16 Asf[64][264];   // 33 KB
  __shared__ u16 BsA[64][42];
  __shared__ u16 BsV[64][42];
  __shared__ float red1[64][4];
  __shared__ float red2[64][4];
  int tid = threadIdx.x;
  int w = tid >> 6, lane = tid & 63;
  int bm = blockIdx.x * 64, bn = blockIdx.y * 64;   // bn in [0,1024)

  // ---- in-block LN of outqf rows [bm, bm+64) ----
  {
    int r = tid >> 2, qt = tid & 3;
    const float* src = outqf + (size_t)(bm + r)*DM_ + qt*64;
    float v[64];
    float s1 = 0.f, s2 = 0.f;
#pragma unroll
    for (int i = 0; i < 64; ++i) { v[i] = src[i]; s1 += v[i]; s2 += v[i]*v[i]; }
    red1[r][qt] = s1; red2[r][qt] = s2;
    __syncthreads();
    float t1 = red1[r][0] + red1[r][1] + red1[r][2] + red1[r][3];
    float t2 = red2[r][0] + red2[r][1] + red2[r][2] + red2[r][3];
    float mean = t1 / (float)DM_;
    float var = fmaxf(t2 / (float)DM_ - mean * mean, 0.f);
    float rstd = rsqrtf(var + 1e-5f);
#pragma unroll
    for (int i = 0; i < 64; ++i) {
      int col = qt*64 + i;
      Asf[r][col] = f2bf((v[i] - mean) * rstd * ldi<F32>(fnw, col)
                         + ldi<F32>(fnb, col));
    }
    __syncthreads();
  }

  f32x4 accA[4], accV[4];
#pragma unroll
  for (int j = 0; j < 4; ++j) {
    accA[j] = (f32x4){0.f, 0.f, 0.f, 0.f};
    accV[j] = (f32x4){0.f, 0.f, 0.f, 0.f};
  }
  int bkl = tid >> 3, bns = (tid & 7) * 8;

  for (int k0 = 0; k0 < DM_; k0 += 32) {
    {
      size_t bbase = (size_t)(k0 + bkl) * 2048 + bn + bns;
      u16x8 ba8 = *(const u16x8*)(b1w + bbase);          // 16B-aligned
      u16x8 bv8 = *(const u16x8*)(b1w + bbase + 1024);
#pragma unroll
      for (int i = 0; i < 8; ++i) {
        BsA[bns + i][bkl] = ba8[i];
        BsV[bns + i][bkl] = bv8[i];
      }
    }
    __syncthreads();
    int mrow = w * 16 + (lane & 15);
    int kq = (lane >> 4) * 8;
    bf16x8 af = __builtin_bit_cast(bf16x8, *(const u16x8*)&Asf[mrow][k0 + kq]);
#pragma unroll
    for (int j = 0; j < 4; ++j) {
      bf16x8 ba = __builtin_bit_cast(bf16x8, *(const u16x8*)&BsA[j*16 + (lane & 15)][kq]);
      bf16x8 bv = __builtin_bit_cast(bf16x8, *(const u16x8*)&BsV[j*16 + (lane & 15)][kq]);
      accA[j] = __builtin_amdgcn_mfma_f32_16x16x32_bf16(af, ba, accA[j], 0, 0, 0);
      accV[j] = __builtin_amdgcn_mfma_f32_16x16x32_bf16(af, bv, accV[j], 0, 0, 0);
    }
    __syncthreads();
  }
  int col0 = lane & 15, rbase = (lane >> 4) * 4;
#pragma unroll
  for (int j = 0; j < 4; ++j) {
#pragma unroll
    for (int r = 0; r < 4; ++r) {
      int row = bm + w * 16 + rbase + r;
      int col = bn + j * 16 + col0;
      float a = accA[j][r] + ldi<F32>(b1, col);
      float v = accV[j][r] + ldi<F32>(b1, col + 1024);
      float ge = 0.5f * a * (1.f + erff(a * 0.70710678118f));
      ug[(size_t)row*1024 + col] = f2bf(ge * v);
    }
  }
}
__global__ __launch_bounds__(256) void fc1g_kernel(
    const int* fl, const float* outqf, const void* fnw, const void* fnb,
    const u16* b1w, const void* b1, u16* ug) {
  if (*fl) fc1g_body<true>(outqf, fnw, fnb, b1w, b1, ug);
  else     fc1g_body<false>(outqf, fnw, fnb, b1w, b1, ug);
}

// ---------------- launch ----------------
extern "C" void kernel_launch(void* const* d_in, const int* in_sizes, int n_in,
                              void* d_out, int out_size, void* d_ws, size_t ws_size,
                              hipStream_t stream) {
  const void* queries        = d_in[0];
  const void* anchors        = d_in[1];
  const void* features       = d_in[2];
  const void* pos_embed      = d_in[3];
  const void* key_pos        = d_in[4];
  const void* query_pos      = d_in[5];
  const void* key_proj_w     = d_in[6];
  const void* key_conv_w     = d_in[7];
  const void* key_conv_b     = d_in[8];
  const void* query_proj_w   = d_in[9];
  const void* dist_w1        = d_in[10];
  const void* dist_b1        = d_in[11];
  const void* dist_w2        = d_in[12];
  const void* bc_proj_w      = d_in[13];
  const void* dt_proj_w      = d_in[14];
  const void* dt_bias        = d_in[15];
  const void* A_log          = d_in[16];
  const void* Dvec           = d_in[17];
  const void* key_norm_w     = d_in[18];
  const void* out_key_proj_w = d_in[19];
  const void* query_norm_w   = d_in[20];
  const void* query_norm_b   = d_in[21];
  const void* out_query_proj_w = d_in[22];
  const void* ffn_norm_w     = d_in[23];
  const void* ffn_norm_b     = d_in[24];
  const void* ffn_fc1_w      = d_in[25];
  const void* ffn_fc1_b      = d_in[26];
  const void* ffn_fc2_w      = d_in[27];
  const void* ffn_fc2_b      = d_in[28];

  if (ws_size < WS_FLOATS * sizeof(float)) return;

  float* ws    = (float*)d_ws;
  float* kp    = ws + OFF_KP;
  float* xact  = ws + OFF_XACT;
  float* aw    = ws + OFF_AW;
  float* carr  = ws + OFF_CARR;
  float* qproj = ws + OFF_QPROJ;
  float* yacc  = ws + OFF_YACC;
  float* send  = ws + OFF_SEND;
  float* ptot  = ws + OFF_PTOT;
  float* h0buf = ws + OFF_H0;
  float* hbuf  = ws + OFF_HB;
  u16*   gbuf  = (u16*)(ws + OFF_GBUF);
  float* outqf = ws + OFF_OUTQF;
  float* wprep = ws + OFF_WPREP;
  int*   flag  = (int*)(wprep + 1536);
  u16*   ugbuf = (u16*)(ws + OFF_UG);
  u16*   lnq   = (u16*)(ws + OFF_LNQ);
  u16*   abuf  = (u16*)(ws + OFF_ABUF);
  u16*   aq    = (u16*)(ws + OFF_AQ);
  u16*   bkey  = (u16*)(ws + OFF_BKEY);
  u16*   bq    = (u16*)(ws + OFF_BQ);
  u16*   bok   = (u16*)(ws + OFF_BOK);
  u16*   boq   = (u16*)(ws + OFF_BOQ);
  u16*   b1w   = (u16*)(ws + OFF_B1W);
  u16*   b2w   = (u16*)(ws + OFF_B2W);

  void* out_q = d_out;
  void* out_feat_bf16 = (void*)((u16*)d_out + (size_t)BSZ_*NQ_*DM_);
  void* out_feat_f32  = (void*)((float*)d_out + (size_t)BSZ_*NQ_*DM_);

  // 1. setup: yacc zero + cast0 + detect/prep
  setup_kernel<<<1249, 256, 0, stream>>>(
      features, pos_embed, abuf, queries, query_pos, aq,
      key_proj_w, bkey, query_proj_w, bq,
      A_log, dt_bias, dist_w1, dist_b1, dist_w2, bc_proj_w, dt_proj_w, wprep,
      yacc, flag);

  // 2. kp = abuf @ bkey : (4096 x 1034), K=256
  kp_gemm_kernel<<<dim3(64, 17), 256, 0, stream>>>(abuf, bkey, kp);

  // 3. dist + conv + qproj GEMM (merged: all depend only on kp/wprep/aq/bq)
  cdq_kernel<<<2048 + 4096 + 32, 256, 0, stream>>>(
      flag, kp, key_conv_w, key_conv_b, xact, aq, bq, qproj,
      anchors, key_pos, wprep, aw, carr);

  // 4. s1 group-LDS-staged
  s1m_kernel<<<dim3(8, NCHUNK_, BSZ_*NH_), 256, 0, stream>>>(aw, xact, send, ptot);

  // 5. s2
  s2_kernel<<<1024, 256, 0, stream>>>(qproj, ptot, send, h0buf, hbuf);

  // 6. s3 group-LDS-staged (control, unchanged) + cast1
  s3cast_kernel<<<2048 + 512, 256, 0, stream>>>(
      flag, aw, carr, xact, h0buf, yacc,
      out_key_proj_w, bok, out_query_proj_w, boq, ffn_fc1_w, b1w, ffn_fc2_w, b2w);

  // 7. g + lnq
  glnq_kernel<<<4096 + 256, 256, 0, stream>>>(
      flag, yacc, xact, kp, Dvec, key_norm_w, gbuf,
      hbuf, query_norm_w, query_norm_b, lnq);

  // 8. out_feat GEMM + outq GEMM
  ofoq_kernel<<<256 + 16, 256, 0, stream>>>(
      flag, gbuf, bok, out_feat_f32, out_feat_bf16, features,
      lnq, boq, outqf, queries);

  // 9. fc1 + gelu with in-block FFN LN (lnf kernel removed)
  fc1g_kernel<<<dim3(4, 16), 256, 0, stream>>>(
      flag, outqf, ffn_norm_w, ffn_norm_b, b1w, ffn_fc1_b, ugbuf);

  // 10. fc2: out_q = outqf + ug @ b2w + b2
  fc2_kernel<<<16, 256, 0, stream>>>(flag, ugbuf, b2w, out_q, outqf, ffn_fc2_b);
}

// Round 10
// 380.268 us; speedup vs baseline: 1.1514x; 1.1514x over previous
//
#include <hip/hip_runtime.h>

typedef unsigned short u16;
typedef __bf16 bf16x8 __attribute__((ext_vector_type(8)));
typedef u16 u16x8 __attribute__((ext_vector_type(8)));
typedef u16 u16x2 __attribute__((ext_vector_type(2)));
typedef float f32x4 __attribute__((ext_vector_type(4)));
typedef float f32x2 __attribute__((ext_vector_type(2)));

#define BSZ_ 2
#define NQ_ 128
#define LSEQ_ 2048
#define DM_ 256
#define DI_ 512
#define NH_ 8
#define HD_ 64
#define DKEY_ 1034
#define DCV_ 514
#define NCHUNK_ 16
#define CT_ 128   // chunk length

__device__ __forceinline__ float bf2f(u16 u) {
  unsigned v = ((unsigned)u) << 16;
  return __builtin_bit_cast(float, v);
}
__device__ __forceinline__ u16 f2bf(float f) {
  unsigned u = __builtin_bit_cast(unsigned, f);
  u += 0x7fffu + ((u >> 16) & 1u);
  return (u16)(u >> 16);
}
__device__ __forceinline__ float sigmoidf_(float x) { return 1.f / (1.f + expf(-x)); }
__device__ __forceinline__ float softplusf_(float x) {
  return (x > 20.f) ? x : log1pf(expf(x));
}

template<bool F32>
__device__ __forceinline__ float ldi(const void* p, size_t i) {
  return F32 ? ((const float*)p)[i] : bf2f(((const u16*)p)[i]);
}
template<bool F32>
__device__ __forceinline__ void sto(void* p, size_t i, float v) {
  if (F32) ((float*)p)[i] = v;
  else ((u16*)p)[i] = f2bf(v);
}

// per-wave dtype detection (all waves read same 64 u16s -> uniform result)
__device__ __forceinline__ bool detect_f32(const void* feat) {
  int lane = threadIdx.x & 63;
  float a = fabsf(bf2f(((const u16*)feat)[2*lane]));
  bool plaus = (a > 1e-6f) && (a < 1e6f);
  unsigned long long m = __ballot(plaus);
  return __popcll(m) < 32;   // true => fp32 storage
}

// ---------------- workspace layout (float units) ----------------
constexpr size_t SZ_KP    = (size_t)BSZ_*LSEQ_*DKEY_;
constexpr size_t SZ_XACT  = (size_t)BSZ_*LSEQ_*DCV_;
constexpr size_t SZ_AW    = (size_t)BSZ_*NH_*LSEQ_*NQ_*2;
constexpr size_t SZ_CARR  = (size_t)BSZ_*LSEQ_*NQ_;
constexpr size_t SZ_QPROJ = (size_t)BSZ_*NQ_*DI_;
constexpr size_t SZ_YACC  = (size_t)BSZ_*LSEQ_*DI_;
constexpr size_t SZ_SEND  = (size_t)BSZ_*NH_*2*NCHUNK_*NQ_*HD_;
constexpr size_t SZ_PTOT  = (size_t)BSZ_*NH_*2*NCHUNK_*NQ_;
constexpr size_t SZ_H0    = SZ_SEND;
constexpr size_t SZ_HB    = (size_t)BSZ_*NH_*2*NQ_*HD_;
constexpr size_t SZ_GBUF  = (size_t)BSZ_*LSEQ_*DI_/2;
constexpr size_t SZ_OUTQF = (size_t)BSZ_*NQ_*DM_;
constexpr size_t SZ_WPREP = 2048;

constexpr size_t OFF_KP    = 0;
constexpr size_t OFF_XACT  = OFF_KP + SZ_KP;
constexpr size_t OFF_AW    = OFF_XACT + SZ_XACT;
constexpr size_t OFF_CARR  = OFF_AW + SZ_AW;
constexpr size_t OFF_QPROJ = OFF_CARR + SZ_CARR;
constexpr size_t OFF_YACC  = OFF_QPROJ + SZ_QPROJ;
constexpr size_t OFF_SEND  = OFF_YACC + SZ_YACC;
constexpr size_t OFF_PTOT  = OFF_SEND + SZ_SEND;
constexpr size_t OFF_H0    = OFF_PTOT + SZ_PTOT;
constexpr size_t OFF_HB    = OFF_H0 + SZ_H0;
constexpr size_t OFF_GBUF  = OFF_HB + SZ_HB;
constexpr size_t OFF_OUTQF = OFF_GBUF + SZ_GBUF;
constexpr size_t OFF_WPREP = OFF_OUTQF + SZ_OUTQF;
constexpr size_t WS_FLOATS = OFF_WPREP + SZ_WPREP;

// FFN/outq scratch aliases into AW (dead after s3):
constexpr size_t OFF_UG  = OFF_AW;                         // 256x1024 bf16
constexpr size_t OFF_LNQ = OFF_UG + (size_t)256*1024/2;    // 256x512 bf16

// Transient bf16 cast buffers alias SEND (dead until s1 writes it):
constexpr size_t OFF_ABUF = OFF_SEND;                         // 4096x256 bf16
constexpr size_t OFF_AQ   = OFF_ABUF + (size_t)4096*256/2;
constexpr size_t OFF_BKEY = OFF_AQ + (size_t)256*256/2;
constexpr size_t OFF_BQ   = OFF_BKEY + (size_t)(256*1034+1)/2 + 1;
// Late bf16 weight casts alias SEND (dead after s2):
constexpr size_t OFF_BOK  = OFF_SEND;
constexpr size_t OFF_BOQ  = OFF_BOK + (size_t)512*256/2;
constexpr size_t OFF_B1W  = OFF_BOQ + (size_t)512*256/2;
constexpr size_t OFF_B2W  = OFF_B1W + (size_t)256*2048/2;

// wprep layout: [0..7] A=-exp(A_log); [8..15] dt_bias; [32..287] w1b; [288..1311] w2;
// [1312..1343] bc_proj; [1344..1471] dt_proj
template<bool F32>
__device__ void prep_body(const void* A_log, const void* dt_bias,
                          const void* w1, const void* b1, const void* w2,
                          const void* bcw, const void* dtw, float* wp) {
  int t = threadIdx.x;
  if (t < 8) {
    wp[t]     = -expf(ldi<F32>(A_log, t));
    wp[8 + t] = ldi<F32>(dt_bias, t);
  }
  if (t < 64) {
    wp[32 + t*4 + 0] = ldi<F32>(w1, 0*64 + t);
    wp[32 + t*4 + 1] = ldi<F32>(w1, 1*64 + t);
    wp[32 + t*4 + 2] = ldi<F32>(w1, 2*64 + t);
    wp[32 + t*4 + 3] = ldi<F32>(b1, t);
  }
  for (int i = t; i < 1024; i += 256) wp[288 + i] = ldi<F32>(w2, i);
  if (t < 32)  wp[1312 + t] = ldi<F32>(bcw, t);
  if (t < 128) wp[1344 + t] = ldi<F32>(dtw, t);
}

// cast helper: d[i] = bf16(s0[i] (+ s1_[i]))
__device__ __forceinline__ void cast_job(bool F32, const void* s0, const void* s1_,
                                         u16* d, size_t n, size_t base, size_t stride) {
  for (size_t i = base; i < n; i += stride) {
    float v = F32 ? ((const float*)s0)[i] : bf2f(((const u16*)s0)[i]);
    if (s1_) v += F32 ? ((const float*)s1_)[i] : bf2f(((const u16*)s1_)[i]);
    d[i] = f2bf(v);
  }
}

// ---------------- setup: yacc zero + cast0 + detect/prep (fused) ----------------
__global__ __launch_bounds__(256) void setup_kernel(
    const void* feat, const void* pe, u16* abuf,
    const void* q, const void* qp, u16* aq,
    const void* kw, u16* bkey, const void* qw, u16* bq,
    const void* A_log, const void* dt_bias, const void* w1, const void* b1,
    const void* w2, const void* bcw, const void* dtw, float* wp,
    float* yacc, int* flag)
{
  int bx = blockIdx.x, tid = threadIdx.x;
  if (bx < 512) {                       // yacc zero: 512 blocks x 4096 floats
    size_t base = (size_t)bx * 4096 + tid;
#pragma unroll
    for (int k = 0; k < 16; ++k) yacc[base + (size_t)k*256] = 0.f;
    return;
  }
  bool F32 = detect_f32(feat);
  if (bx < 1024) {                      // abuf = bf16(features + pos_embed)
    cast_job(F32, feat, pe, abuf, (size_t)4096*256,
             (size_t)(bx-512)*256 + tid, (size_t)512*256);
  } else if (bx < 1056) {               // aq = bf16(queries + query_pos)
    cast_job(F32, q, qp, aq, (size_t)256*256,
             (size_t)(bx-1024)*256 + tid, (size_t)32*256);
  } else if (bx < 1184) {               // bkey = bf16(key_proj_w)
    cast_job(F32, kw, nullptr, bkey, (size_t)256*1034,
             (size_t)(bx-1056)*256 + tid, (size_t)128*256);
  } else if (bx < 1248) {               // bq = bf16(query_proj_w)
    cast_job(F32, qw, nullptr, bq, (size_t)256*512,
             (size_t)(bx-1184)*256 + tid, (size_t)64*256);
  } else {                              // detect-store + prep
    if (tid == 0) *flag = F32 ? 1 : 0;
    if (F32) prep_body<true>(A_log, dt_bias, w1, b1, w2, bcw, dtw, wp);
    else     prep_body<false>(A_log, dt_bias, w1, b1, w2, bcw, dtw, wp);
  }
}

// ---------------- MFMA GEMM body (Bs padded to 42: bank-conflict-free) ----------
// BV: B-stage vector width. 2 = unconditional u16x8 (row stride 16B-aligned,
// tiles always full: N in {256,512,1024,2048}); 1 = guarded 4x u16x2
// (4B-aligned only, N=1034); 0 = scalar fallback.
template<int A_MODE, int B_MODE, int BV, int OUT_EEXT, int RES_EXT, int RES_F32, int BIAS, bool F32>
__device__ void gemm_body(int bm, int bn,
                          const void* A0, const void* A1, const void* Bw,
                          float* Cf, void* Cext, const void* ResE,
                          const float* ResF, const void* Bias,
                          int M, int N, int K) {
  __shared__ u16 As[64][40];
  __shared__ u16 Bs[64][42];
  int tid = threadIdx.x;
  int w = tid >> 6, lane = tid & 63;
  f32x4 acc[4];
#pragma unroll
  for (int j = 0; j < 4; ++j) acc[j] = (f32x4){0.f, 0.f, 0.f, 0.f};

  int arow = tid >> 2, aseg = (tid & 3) * 8;
  int bkl = tid >> 3, bns = (tid & 7) * 8;

  for (int k0 = 0; k0 < K; k0 += 32) {
    {
      size_t abase = (size_t)(bm + arow) * K + k0 + aseg;
      u16x8 tv;
      if (A_MODE == 0) {
#pragma unroll
        for (int i = 0; i < 8; ++i)
          tv[i] = f2bf(ldi<F32>(A0, abase + i) + ldi<F32>(A1, abase + i));
      } else {
        tv = *(const u16x8*)((const u16*)A0 + abase);   // 16B-aligned for all uses
      }
      *(u16x8*)&As[arow][aseg] = tv;
    }
    {
      size_t bbase = (size_t)(k0 + bkl) * N + bn + bns;
      if (BV == 2) {
        u16x8 bv8 = *(const u16x8*)((const u16*)Bw + bbase);
#pragma unroll
        for (int i = 0; i < 8; ++i) Bs[bns + i][bkl] = bv8[i];
      } else if (BV == 1 && bn + bns + 8 <= N) {
        const u16* bp = (const u16*)Bw + bbase;
#pragma unroll
        for (int i2 = 0; i2 < 4; ++i2) {
          u16x2 v2 = *(const u16x2*)(bp + i2*2);
          Bs[bns + i2*2][bkl]     = v2[0];
          Bs[bns + i2*2 + 1][bkl] = v2[1];
        }
      } else {
#pragma unroll
        for (int i = 0; i < 8; ++i) {
          u16 v;
          if (bn + bns + i < N) {
            if (B_MODE == 1) v = ((const u16*)Bw)[bbase + i];
            else             v = f2bf(ldi<F32>(Bw, bbase + i));
          } else v = (u16)0;
          Bs[bns + i][bkl] = v;
        }
      }
    }
    __syncthreads();
    int mrow = w * 16 + (lane & 15);
    int kq = (lane >> 4) * 8;
    bf16x8 af = __builtin_bit_cast(bf16x8, *(const u16x8*)&As[mrow][kq]);
#pragma unroll
    for (int j = 0; j < 4; ++j) {
      bf16x8 bfv = __builtin_bit_cast(bf16x8, *(const u16x8*)&Bs[j*16 + (lane & 15)][kq]);
      acc[j] = __builtin_amdgcn_mfma_f32_16x16x32_bf16(af, bfv, acc[j], 0, 0, 0);
    }
    __syncthreads();
  }
  int col0 = lane & 15, rbase = (lane >> 4) * 4;
#pragma unroll
  for (int j = 0; j < 4; ++j) {
#pragma unroll
    for (int r = 0; r < 4; ++r) {
      int row = bm + w * 16 + rbase + r;
      int col = bn + j * 16 + col0;
      if (col < N) {
        size_t idx = (size_t)row * N + col;
        float v = acc[j][r];
        if (BIAS)     v += ldi<F32>(Bias, col);
        if (RES_EXT)  v += ldi<F32>(ResE, idx);
        if (RES_F32)  v += ResF[idx];
        if (OUT_EEXT) sto<F32>(Cext, idx, v);
        else          Cf[idx] = v;
      }
    }
  }
}

// kp = abuf @ bkey (all-internal bf16, fp32 out); N=1034 -> BV=1 (4B-aligned)
__global__ __launch_bounds__(256) void kp_gemm_kernel(
    const u16* abuf, const u16* bkey, float* kp) {
  gemm_body<1,1,1,0,0,0,0,false>(blockIdx.x*64, blockIdx.y*64, abuf, nullptr, bkey,
                                 kp, nullptr, nullptr, nullptr, nullptr,
                                 4096, DKEY_, DM_);
}

// fc2: out_q = outqf + ug @ b2w + b2
template<bool F32>
__device__ void fc2_body(const u16* ug, const u16* b2w, void* out_q,
                         const float* outqf, const void* b2) {
  gemm_body<1,1,2,1,0,1,1,F32>((blockIdx.x&3)*64, (blockIdx.x>>2)*64, ug, nullptr,
                               b2w, nullptr, out_q, nullptr, outqf, b2,
                               BSZ_*NQ_, DM_, 1024);
}
__global__ __launch_bounds__(256) void fc2_kernel(
    const int* fl, const u16* ug, const u16* b2w, void* out_q,
    const float* outqf, const void* b2) {
  if (*fl) fc2_body<true>(ug, b2w, out_q, outqf, b2);
  else     fc2_body<false>(ug, b2w, out_q, outqf, b2);
}

// ---------------- conv + qproj GEMM (fused, independent blocks; r8 structure) ---
template<bool F32>
__device__ void conv_body(const float* kp, const void* cw, const void* cb,
                          float* xact) {
  int row = blockIdx.x;
  int l = row & (LSEQ_ - 1);
  for (int ch = threadIdx.x; ch < DCV_; ch += 256) {
    float acc = ldi<F32>(cb, ch);
#pragma unroll
    for (int k = 0; k < 4; ++k) {
      int ll = l - 3 + k;
      if (ll >= 0)
        acc = fmaf(ldi<F32>(cw, ch*4 + k), kp[(size_t)(row - 3 + k)*DKEY_ + DI_ + ch], acc);
    }
    xact[(size_t)row*DCV_ + ch] = acc * sigmoidf_(acc);
  }
}
__global__ __launch_bounds__(256) void convqp_kernel(
    const int* fl, const float* kp, const void* cw, const void* cb, float* xact,
    const u16* aq, const u16* bq, float* qproj)
{
  int bx = blockIdx.x;
  if (bx < 4096) {
    if (*fl) conv_body<true>(kp, cw, cb, xact);
    else     conv_body<false>(kp, cw, cb, xact);
  } else {
    int i = bx - 4096;   // 32 blocks: M=256 (4 tiles) x N=512 (8 tiles)
    gemm_body<1,1,2,0,0,0,0,false>((i&3)*64, (i>>2)*64, aq, nullptr, bq,
                                   qproj, nullptr, nullptr, nullptr, nullptr,
                                   BSZ_*NQ_, DI_, DM_);
  }
}

// ---------------- dist MLP -> a, w, c (standalone, own regalloc; r8) -----------
template<bool F32>
__device__ void dist_body(const void* anchors, const void* key_pos,
                          const float* kp, const float* xact, const float* wp,
                          float* aw, float* carr) {
  int tid = threadIdx.x;
  int n = tid & 127;
  int idx = blockIdx.x;
  int b = idx >> 10;
  int l = ((idx & 1023) << 1) | (tid >> 7);
  size_t row = (size_t)b * LSEQ_ + l;

  float enc0, enc1, enc2;
  {
    float e[3];
#pragma unroll
    for (int d = 0; d < 3; ++d) {
      float delta = ldi<F32>(anchors, (b*NQ_ + n)*3 + d) - ldi<F32>(key_pos, row*3 + d);
      float s = delta < 0.f ? -1.f : 1.f;
      e[d] = s * log2f(fabsf(delta) * 20.f + 1.f) * (1.f/12.f);
    }
    enc0 = e[0]; enc1 = e[1]; enc2 = e[2];
  }
  float feat[16];
#pragma unroll
  for (int f = 0; f < 16; ++f) feat[f] = 0.f;
  for (int j = 0; j < 64; ++j) {
    float w0 = wp[32 + j*4], w1v = wp[33 + j*4], w2v = wp[34 + j*4], bb = wp[35 + j*4];
    float hj = fmaxf(fmaf(enc0, w0, fmaf(enc1, w1v, fmaf(enc2, w2v, bb))), 0.f);
#pragma unroll
    for (int f = 0; f < 16; ++f) feat[f] = fmaf(hj, wp[288 + j*16 + f], feat[f]);
  }
  float bc0 = 0.f, bc1 = 0.f;
#pragma unroll
  for (int f = 0; f < 16; ++f) {
    bc0 = fmaf(feat[f], wp[1312 + f*2], bc0);
    bc1 = fmaf(feat[f], wp[1313 + f*2], bc1);
  }
  float bb_ = xact[row*DCV_ + DI_];
  float cb_ = xact[row*DCV_ + DI_ + 1];
  float Bs = bc0 + bb_, Cs = bc1 + cb_;
  carr[row*NQ_ + n] = Cs;

  float dtb[8];
#pragma unroll
  for (int h = 0; h < 8; ++h) dtb[h] = 0.f;
#pragma unroll
  for (int f = 0; f < 16; ++f)
#pragma unroll
    for (int h = 0; h < 8; ++h) dtb[h] = fmaf(feat[f], wp[1344 + f*8 + h], dtb[h]);

#pragma unroll
  for (int h = 0; h < 8; ++h) {
    float xln = dtb[h] + kp[row*DKEY_ + (DI_*2 + 2) + h] + wp[8 + h];
    float dtv = softplusf_(xln);
    float a = expf(dtv * wp[h]);
    float wv = dtv * Bs;
    size_t o = (((size_t)(b*NH_ + h)*LSEQ_ + l)*NQ_ + n)*2;
    aw[o] = a;
    aw[o + 1] = wv;
  }
}
__global__ __launch_bounds__(256) void dist_kernel(
    const int* fl, const void* anchors, const void* key_pos, const float* kp,
    const float* xact, const float* wp, float* aw, float* carr) {
  if (*fl) dist_body<true>(anchors, key_pos, kp, xact, wp, aw, carr);
  else     dist_body<false>(anchors, key_pos, kp, xact, wp, aw, carr);
}

// ---------------- scan phase 1: group-LDS-staged ----------------
__global__ __launch_bounds__(256) void s1m_kernel(
    const float* __restrict__ aw, const float* __restrict__ xact,
    float* __restrict__ send, float* __restrict__ ptot)
{
  __shared__ float awl[2][8][32];   // 2 KB: 16 n x 2 floats per step
  __shared__ float xl [2][8][64];   // 4 KB
  int tid = threadIdx.x;
  int hd = tid & 63;
  int w = __builtin_amdgcn_readfirstlane(tid >> 6);
  int ns = blockIdx.x, q = blockIdx.y, z = blockIdx.z;   // z = b*NH_ + h
  int h = z & 7, b = z >> 3;
  int n0 = __builtin_amdgcn_readfirstlane(ns*16 + w*4);

  float hf[4], hb[4], pr[4];
#pragma unroll
  for (int i = 0; i < 4; ++i) { hf[i] = 0.f; hb[i] = 0.f; pr[i] = 1.f; }

  // stage thread mapping: s8 = step-in-group (0..7), j = 0..31
  int s8 = tid >> 5, j = tid & 31;
  int t0 = q*CT_;
  const float* awg = aw + (size_t)z*LSEQ_*(NQ_*2)
                     + (size_t)(t0 + s8)*(NQ_*2) + ns*32 + j;
  const float* xg  = xact + ((size_t)(b*LSEQ_) + t0 + s8)*DCV_ + (h<<6) + j*2;
  const long awgstep = 8L*(NQ_*2);
  const long xgstep  = 8L*DCV_;

  // prologue: stage group 0
  {
    float pa = *awg;
    f32x2 px = *(const f32x2*)xg;
    awg += awgstep; xg += xgstep;
    awl[0][s8][j] = pa;
    *(f32x2*)&xl[0][s8][j*2] = px;
  }
  asm volatile("s_waitcnt lgkmcnt(0)" ::: "memory");
  __builtin_amdgcn_s_barrier();

  int p = 0;
  float sa; f32x2 sx;
  for (int g = 0; g < 16; ++g) {
    if (g < 15) {
      sa = *awg; sx = *(const f32x2*)xg;
      awg += awgstep; xg += xgstep;
    }
#pragma unroll
    for (int s = 0; s < 8; ++s) {
      const float* A = &awl[p][s][w*8];
      float xv = xl[p][s][hd];
#pragma unroll
      for (int i = 0; i < 4; ++i) {
        float a = A[2*i], wv = A[2*i + 1];
        float wx = wv * xv;
        hf[i] = fmaf(hf[i], a, wx);
        hb[i] = fmaf(pr[i], wx, hb[i]);
        pr[i] *= a;
      }
    }
    if (g < 15) {
      awl[p^1][s8][j] = sa;
      *(f32x2*)&xl[p^1][s8][j*2] = sx;
    }
    asm volatile("s_waitcnt lgkmcnt(0)" ::: "memory");
    __builtin_amdgcn_s_barrier();
    p ^= 1;
  }

  size_t cbf = (size_t)((z*2 + 0)*NCHUNK_ + q);
  size_t cbb = (size_t)((z*2 + 1)*NCHUNK_ + (NCHUNK_ - 1 - q));
#pragma unroll
  for (int i = 0; i < 4; ++i) {
    send[cbf*(NQ_*HD_) + (size_t)(n0 + i)*HD_ + hd] = hf[i];
    send[cbb*(NQ_*HD_) + (size_t)(n0 + i)*HD_ + hd] = hb[i];
  }
  if (hd == 0) {
#pragma unroll
    for (int i = 0; i < 4; ++i) {
      ptot[cbf*NQ_ + n0 + i] = pr[i];
      ptot[cbb*NQ_ + n0 + i] = pr[i];
    }
  }
}

// ---------------- scan phase 2 ----------------
__global__ __launch_bounds__(256) void s2_kernel(
    const float* __restrict__ qproj, const float* __restrict__ ptot,
    const float* __restrict__ send, float* __restrict__ h0buf,
    float* __restrict__ hbuf)
{
  int g = blockIdx.x*256 + threadIdx.x;
  int hd = g & 63;
  int n = (g >> 6) & 127;
  int dir = (g >> 13) & 1;
  int h = (g >> 14) & 7;
  int b = g >> 17;
  float hcur = qproj[((size_t)(b*NQ_ + n))*DI_ + h*HD_ + hd];
  size_t base = (size_t)((b*NH_ + h)*2 + dir) * NCHUNK_;
  for (int q = 0; q < NCHUNK_; ++q) {
    size_t cb = base + q;
    h0buf[cb*(NQ_*HD_) + (size_t)n*HD_ + hd] = hcur;
    hcur = fmaf(hcur, ptot[cb*NQ_ + n], send[cb*(NQ_*HD_) + (size_t)n*HD_ + hd]);
  }
  hbuf[((size_t)((b*NH_ + h)*2 + dir))*(NQ_*HD_) + (size_t)n*HD_ + hd] = hcur;
}

// ---------------- scan phase 3: group-LDS-staged (PROVEN ~87us, control) -------
template<bool F32>
__device__ void cast1_part(const void* okw, u16* bok, const void* oqw, u16* boq,
                           const void* w1, u16* b1w, const void* w2, u16* b2w) {
  int i = blockIdx.x - 2048;
  int job = i >> 7, bj = i & 127;
  size_t base = (size_t)bj*256 + threadIdx.x, stride = (size_t)128*256;
  switch (job) {
    case 0: cast_job(F32, okw, nullptr, bok, (size_t)512*256, base, stride); break;
    case 1: cast_job(F32, oqw, nullptr, boq, (size_t)512*256, base, stride); break;
    case 2: cast_job(F32, w1, nullptr, b1w, (size_t)256*2048, base, stride); break;
    default: cast_job(F32, w2, nullptr, b2w, (size_t)1024*256, base, stride); break;
  }
}
__global__ __launch_bounds__(256) void s3cast_kernel(
    const int* fl, const float* __restrict__ aw, const float* __restrict__ carr,
    const float* __restrict__ xact, const float* __restrict__ h0buf,
    float* __restrict__ yacc,
    const void* okw, u16* bok, const void* oqw, u16* boq,
    const void* w1, u16* b1w, const void* w2, u16* b2w)
{
  int bx = blockIdx.x;
  if (bx >= 2048) {
    if (*fl) cast1_part<true>(okw, bok, oqw, boq, w1, b1w, w2, b2w);
    else     cast1_part<false>(okw, bok, oqw, boq, w1, b1w, w2, b2w);
    return;
  }
  __shared__ float awl[2][8][64];   // 4 KB
  __shared__ float ctl[2][8][32];   // 2 KB
  __shared__ float xl [2][8][64];   // 4 KB
  __shared__ float yl [8][4][64];   // 8 KB

  int tid = threadIdx.x;
  int hd = tid & 63;
  int w = __builtin_amdgcn_readfirstlane(tid >> 6);
  int ns = bx & 3, q = (bx >> 2) & 15, zz = bx >> 6;
  int dir = zz & 1, h = (zz >> 1) & 7, b = zz >> 4;
  int z = b*NH_ + h;
  int n0 = ns*32 + w*8;

  int tbase = dir ? (LSEQ_ - 1 - q*CT_) : (q*CT_);
  int tstep = dir ? -1 : 1;

  // stage thread mapping: s8 = step-in-group, j = 0..31
  int s8 = tid >> 5, j = tid & 31;
  const float* awg = aw + (size_t)z*LSEQ_*(NQ_*2)
                     + (size_t)(tbase + tstep*s8)*(NQ_*2) + ns*64 + j*2;
  const float* ctg = carr + ((size_t)(b*LSEQ_) + tbase + tstep*s8)*NQ_ + ns*32 + j;
  const float* xg  = xact + ((size_t)(b*LSEQ_) + tbase + tstep*s8)*DCV_ + (h<<6) + j*2;
  long awgstep = (long)tstep*8*(NQ_*2);
  long ctgstep = (long)tstep*8*NQ_;
  long xgstep  = (long)tstep*8*DCV_;

  // prologue: issue stage(group 0) loads first (deep), then h0 state loads
  f32x2 pa = *(const f32x2*)awg;
  float pc = *ctg;
  f32x2 px = *(const f32x2*)xg;
  awg += awgstep; ctg += ctgstep; xg += xgstep;

  float h0_, h1_, h2_, h3_, h4_, h5_, h6_, h7_;
  {
    size_t cb = (size_t)((z*2 + dir)*NCHUNK_ + q);
    const float* hp = h0buf + cb*(NQ_*HD_) + (size_t)n0*HD_ + hd;
    h0_ = hp[0*HD_]; h1_ = hp[1*HD_]; h2_ = hp[2*HD_]; h3_ = hp[3*HD_];
    h4_ = hp[4*HD_]; h5_ = hp[5*HD_]; h6_ = hp[6*HD_]; h7_ = hp[7*HD_];
  }
  *(f32x2*)&awl[0][s8][j*2] = pa;
  ctl[0][s8][j] = pc;
  *(f32x2*)&xl[0][s8][j*2] = px;
  asm volatile("s_waitcnt lgkmcnt(0)" ::: "memory");
  __builtin_amdgcn_s_barrier();

  float* yrow = yacc + ((size_t)(b*LSEQ_) + tbase)*DI_ + (h << 6) + hd;
  long ystep = (long)tstep * DI_;

  int p = 0;
  f32x2 sa; float sc; f32x2 sx;
  for (int g = 0; g < 16; ++g) {
    if (g < 15) {
      sa = *(const f32x2*)awg; sc = *ctg; sx = *(const f32x2*)xg;
      awg += awgstep; ctg += ctgstep; xg += xgstep;
    }
    if (g > 0) {
#pragma unroll
      for (int r = 0; r < 2; ++r) {
        int s = w + r*4;
        float yv = yl[s][0][hd] + yl[s][1][hd] + yl[s][2][hd] + yl[s][3][hd];
        atomicAdd(yrow + (long)((g-1)*8 + s)*ystep, 0.5f * yv);
      }
    }
    asm volatile("s_waitcnt lgkmcnt(0)" ::: "memory");
    __builtin_amdgcn_s_barrier();           // yl reads done before overwrite
#pragma unroll
    for (int s = 0; s < 8; ++s) {
      const float* A = &awl[p][s][w*16];
      const float* C = &ctl[p][s][w*8];
      float xv = xl[p][s][hd];
      float ya, yb;
      h0_ = fmaf(h0_, A[0],  A[1]*xv);  ya = h0_ * C[0];
      h1_ = fmaf(h1_, A[2],  A[3]*xv);  yb = h1_ * C[1];
      h2_ = fmaf(h2_, A[4],  A[5]*xv);  ya = fmaf(h2_, C[2], ya);
      h3_ = fmaf(h3_, A[6],  A[7]*xv);  yb = fmaf(h3_, C[3], yb);
      h4_ = fmaf(h4_, A[8],  A[9]*xv);  ya = fmaf(h4_, C[4], ya);
      h5_ = fmaf(h5_, A[10], A[11]*xv); yb = fmaf(h5_, C[5], yb);
      h6_ = fmaf(h6_, A[12], A[13]*xv); ya = fmaf(h6_, C[6], ya);
      h7_ = fmaf(h7_, A[14], A[15]*xv); yb = fmaf(h7_, C[7], yb);
      yl[s][w][hd] = ya + yb;
    }
    if (g < 15) {
      *(f32x2*)&awl[p^1][s8][j*2] = sa;
      ctl[p^1][s8][j] = sc;
      *(f32x2*)&xl[p^1][s8][j*2] = sx;
    }
    asm volatile("s_waitcnt lgkmcnt(0)" ::: "memory");
    __builtin_amdgcn_s_barrier();           // staged buffer ready for g+1
    p ^= 1;
  }
#pragma unroll
  for (int r = 0; r < 2; ++r) {
    int s = w + r*4;
    float yv = yl[s][0][hd] + yl[s][1][hd] + yl[s][2][hd] + yl[s][3][hd];
    atomicAdd(yrow + (long)(15*8 + s)*ystep, 0.5f * yv);
  }
}

// ---------------- block reduction helper ----------------
__device__ __forceinline__ float block_sum256(float v, float* red) {
#pragma unroll
  for (int off = 32; off; off >>= 1) v += __shfl_xor(v, off, 64);
  int wv = threadIdx.x >> 6;
  if ((threadIdx.x & 63) == 0) red[wv] = v;
  __syncthreads();
  float t = red[0] + red[1] + red[2] + red[3];
  __syncthreads();
  return t;
}

// ---------------- g (gated RMSNorm) + lnq (fused) ----------------
template<bool F32>
__device__ void g_body(const float* yacc, const float* xact, const float* kp,
                       const void* Dv, const void* knw, u16* gbuf) {
  int row = blockIdx.x, tid = threadIdx.x;
  __shared__ float red[4];
  float gg[2];
  float ss = 0.f;
#pragma unroll
  for (int ii = 0; ii < 2; ++ii) {
    int ch = tid + ii*256;
    float yv = yacc[(size_t)row*DI_ + ch];
    float xv = xact[(size_t)row*DCV_ + ch];
    float zv = kp[(size_t)row*DKEY_ + ch];
    float Dh = ldi<F32>(Dv, ch >> 6);
    float yf = yv + 2.f * Dh * xv;
    float g = yf * (zv * sigmoidf_(zv));
    gg[ii] = g;
    ss += g * g;
  }
  float tot = block_sum256(ss, red);
  float r = rsqrtf(tot / (float)DI_ + 1e-5f);
#pragma unroll
  for (int ii = 0; ii < 2; ++ii) {
    int ch = tid + ii*256;
    gbuf[(size_t)row*DI_ + ch] = f2bf(gg[ii] * r * ldi<F32>(knw, ch));
  }
}
template<bool F32>
__device__ void lnq_body(const float* hbuf, const void* qnw, const void* qnb,
                         u16* lnq) {
  int row = blockIdx.x - 4096;
  int b = row >> 7, n = row & 127;
  int tid = threadIdx.x;
  __shared__ float red[4];
  float hv[2];
  float s1 = 0.f, s2 = 0.f;
#pragma unroll
  for (int ii = 0; ii < 2; ++ii) {
    int ch = tid + ii*256;
    int h = ch >> 6, hd = ch & 63;
    size_t base = ((size_t)((b*NH_ + h)*2))*(NQ_*HD_) + (size_t)n*HD_ + hd;
    float v = 0.5f * (hbuf[base] + hbuf[base + (size_t)NQ_*HD_]);
    hv[ii] = v;
    s1 += v;
    s2 += v * v;
  }
  s1 = block_sum256(s1, red);
  s2 = block_sum256(s2, red);
  float mean = s1 / (float)DI_;
  float var = fmaxf(s2 / (float)DI_ - mean * mean, 0.f);
  float rstd = rsqrtf(var + 1e-5f);
#pragma unroll
  for (int ii = 0; ii < 2; ++ii) {
    int ch = tid + ii*256;
    lnq[(size_t)row*DI_ + ch] =
        f2bf((hv[ii] - mean) * rstd * ldi<F32>(qnw, ch) + ldi<F32>(qnb, ch));
  }
}
__global__ __launch_bounds__(256) void glnq_kernel(
    const int* fl, const float* yacc, const float* xact, const float* kp,
    const void* Dv, const void* knw, u16* gbuf,
    const float* hbuf, const void* qnw, const void* qnb, u16* lnq)
{
  if (blockIdx.x < 4096) {
    if (*fl) g_body<true>(yacc, xact, kp, Dv, knw, gbuf);
    else     g_body<false>(yacc, xact, kp, Dv, knw, gbuf);
  } else {
    if (*fl) lnq_body<true>(hbuf, qnw, qnb, lnq);
    else     lnq_body<false>(hbuf, qnw, qnb, lnq);
  }
}

// ---------------- out_feat GEMM + outq GEMM (fused) ----------------
template<bool F32>
__device__ void ofoq_body(const u16* gbuf, const u16* bok, void* out_feat,
                          const void* features, const u16* lnq, const u16* boq,
                          float* outqf, const void* queries) {
  int bx = blockIdx.x;
  if (bx < 256) {   // out_feat: M=4096 (64 tiles) x N=256 (4 tiles), K=512
    gemm_body<1,1,2,1,1,0,0,F32>((bx>>2)*64, (bx&3)*64, gbuf, nullptr, bok,
                                 nullptr, out_feat, features, nullptr, nullptr,
                                 4096, DM_, DI_);
  } else {          // outq: M=256 (4) x N=256 (4), K=512
    int i = bx - 256;
    gemm_body<1,1,2,0,1,0,0,F32>((i&3)*64, (i>>2)*64, lnq, nullptr, boq,
                                 outqf, nullptr, queries, nullptr, nullptr,
                                 BSZ_*NQ_, DM_, DI_);
  }
}
__global__ __launch_bounds__(256) void ofoq_kernel(
    const int* fl, const u16* gbuf, const u16* bok,
    void* out_feat_f32, void* out_feat_bf16, const void* features,
    const u16* lnq, const u16* boq, float* outqf, const void* queries) {
  if (*fl) ofoq_body<true>(gbuf, bok, out_feat_f32, features, lnq, boq, outqf, queries);
  else     ofoq_body<false>(gbuf, bok, out_feat_bf16, features, lnq, boq, outqf, queries);
}

// ---------------- fc1 + gelu, with IN-BLOCK FFN LayerNorm (lnf kernel removed) --
template<bool F32>
__device__ void fc1g_body(const float* outqf, const void* fnw, const void* fnb,
                          const u16* b1w, const void* b1, u16* ug) {
  __shared__ u16 Asf[64][264];   // 33 KB
  __shared__ u16 BsA[64][42];
  __shared__ u16 BsV[64][42];
  __shared__ float red1[64][4];
  __shared__ float red2[64][4];
  int tid = threadIdx.x;
  int w = tid >> 6, lane = tid & 63;
  int bm = blockIdx.x * 64, bn = blockIdx.y * 64;   // bn in [0,1024)

  // ---- in-block LN of outqf rows [bm, bm+64) ----
  {
    int r = tid >> 2, qt = tid & 3;
    const float* src = outqf + (size_t)(bm + r)*DM_ + qt*64;
    float v[64];
    float s1 = 0.f, s2 = 0.f;
#pragma unroll
    for (int i = 0; i < 64; ++i) { v[i] = src[i]; s1 += v[i]; s2 += v[i]*v[i]; }
    red1[r][qt] = s1; red2[r][qt] = s2;
    __syncthreads();
    float t1 = red1[r][0] + red1[r][1] + red1[r][2] + red1[r][3];
    float t2 = red2[r][0] + red2[r][1] + red2[r][2] + red2[r][3];
    float mean = t1 / (float)DM_;
    float var = fmaxf(t2 / (float)DM_ - mean * mean, 0.f);
    float rstd = rsqrtf(var + 1e-5f);
#pragma unroll
    for (int i = 0; i < 64; ++i) {
      int col = qt*64 + i;
      Asf[r][col] = f2bf((v[i] - mean) * rstd * ldi<F32>(fnw, col)
                         + ldi<F32>(fnb, col));
    }
    __syncthreads();
  }

  f32x4 accA[4], accV[4];
#pragma unroll
  for (int j = 0; j < 4; ++j) {
    accA[j] = (f32x4){0.f, 0.f, 0.f, 0.f};
    accV[j] = (f32x4){0.f, 0.f, 0.f, 0.f};
  }
  int bkl = tid >> 3, bns = (tid & 7) * 8;

  for (int k0 = 0; k0 < DM_; k0 += 32) {
    {
      size_t bbase = (size_t)(k0 + bkl) * 2048 + bn + bns;
      u16x8 ba8 = *(const u16x8*)(b1w + bbase);          // 16B-aligned
      u16x8 bv8 = *(const u16x8*)(b1w + bbase + 1024);
#pragma unroll
      for (int i = 0; i < 8; ++i) {
        BsA[bns + i][bkl] = ba8[i];
        BsV[bns + i][bkl] = bv8[i];
      }
    }
    __syncthreads();
    int mrow = w * 16 + (lane & 15);
    int kq = (lane >> 4) * 8;
    bf16x8 af = __builtin_bit_cast(bf16x8, *(const u16x8*)&Asf[mrow][k0 + kq]);
#pragma unroll
    for (int j = 0; j < 4; ++j) {
      bf16x8 ba = __builtin_bit_cast(bf16x8, *(const u16x8*)&BsA[j*16 + (lane & 15)][kq]);
      bf16x8 bv = __builtin_bit_cast(bf16x8, *(const u16x8*)&BsV[j*16 + (lane & 15)][kq]);
      accA[j] = __builtin_amdgcn_mfma_f32_16x16x32_bf16(af, ba, accA[j], 0, 0, 0);
      accV[j] = __builtin_amdgcn_mfma_f32_16x16x32_bf16(af, bv, accV[j], 0, 0, 0);
    }
    __syncthreads();
  }
  int col0 = lane & 15, rbase = (lane >> 4) * 4;
#pragma unroll
  for (int j = 0; j < 4; ++j) {
#pragma unroll
    for (int r = 0; r < 4; ++r) {
      int row = bm + w * 16 + rbase + r;
      int col = bn + j * 16 + col0;
      float a = accA[j][r] + ldi<F32>(b1, col);
      float v = accV[j][r] + ldi<F32>(b1, col + 1024);
      float ge = 0.5f * a * (1.f + erff(a * 0.70710678118f));
      ug[(size_t)row*1024 + col] = f2bf(ge * v);
    }
  }
}
__global__ __launch_bounds__(256) void fc1g_kernel(
    const int* fl, const float* outqf, const void* fnw, const void* fnb,
    const u16* b1w, const void* b1, u16* ug) {
  if (*fl) fc1g_body<true>(outqf, fnw, fnb, b1w, b1, ug);
  else     fc1g_body<false>(outqf, fnw, fnb, b1w, b1, ug);
}

// ---------------- launch ----------------
extern "C" void kernel_launch(void* const* d_in, const int* in_sizes, int n_in,
                              void* d_out, int out_size, void* d_ws, size_t ws_size,
                              hipStream_t stream) {
  const void* queries        = d_in[0];
  const void* anchors        = d_in[1];
  const void* features       = d_in[2];
  const void* pos_embed      = d_in[3];
  const void* key_pos        = d_in[4];
  const void* query_pos      = d_in[5];
  const void* key_proj_w     = d_in[6];
  const void* key_conv_w     = d_in[7];
  const void* key_conv_b     = d_in[8];
  const void* query_proj_w   = d_in[9];
  const void* dist_w1        = d_in[10];
  const void* dist_b1        = d_in[11];
  const void* dist_w2        = d_in[12];
  const void* bc_proj_w      = d_in[13];
  const void* dt_proj_w      = d_in[14];
  const void* dt_bias        = d_in[15];
  const void* A_log          = d_in[16];
  const void* Dvec           = d_in[17];
  const void* key_norm_w     = d_in[18];
  const void* out_key_proj_w = d_in[19];
  const void* query_norm_w   = d_in[20];
  const void* query_norm_b   = d_in[21];
  const void* out_query_proj_w = d_in[22];
  const void* ffn_norm_w     = d_in[23];
  const void* ffn_norm_b     = d_in[24];
  const void* ffn_fc1_w      = d_in[25];
  const void* ffn_fc1_b      = d_in[26];
  const void* ffn_fc2_w      = d_in[27];
  const void* ffn_fc2_b      = d_in[28];

  if (ws_size < WS_FLOATS * sizeof(float)) return;

  float* ws    = (float*)d_ws;
  float* kp    = ws + OFF_KP;
  float* xact  = ws + OFF_XACT;
  float* aw    = ws + OFF_AW;
  float* carr  = ws + OFF_CARR;
  float* qproj = ws + OFF_QPROJ;
  float* yacc  = ws + OFF_YACC;
  float* send  = ws + OFF_SEND;
  float* ptot  = ws + OFF_PTOT;
  float* h0buf = ws + OFF_H0;
  float* hbuf  = ws + OFF_HB;
  u16*   gbuf  = (u16*)(ws + OFF_GBUF);
  float* outqf = ws + OFF_OUTQF;
  float* wprep = ws + OFF_WPREP;
  int*   flag  = (int*)(wprep + 1536);
  u16*   ugbuf = (u16*)(ws + OFF_UG);
  u16*   lnq   = (u16*)(ws + OFF_LNQ);
  u16*   abuf  = (u16*)(ws + OFF_ABUF);
  u16*   aq    = (u16*)(ws + OFF_AQ);
  u16*   bkey  = (u16*)(ws + OFF_BKEY);
  u16*   bq    = (u16*)(ws + OFF_BQ);
  u16*   bok   = (u16*)(ws + OFF_BOK);
  u16*   boq   = (u16*)(ws + OFF_BOQ);
  u16*   b1w   = (u16*)(ws + OFF_B1W);
  u16*   b2w   = (u16*)(ws + OFF_B2W);

  void* out_q = d_out;
  void* out_feat_bf16 = (void*)((u16*)d_out + (size_t)BSZ_*NQ_*DM_);
  void* out_feat_f32  = (void*)((float*)d_out + (size_t)BSZ_*NQ_*DM_);

  // 1. setup: yacc zero + cast0 + detect/prep
  setup_kernel<<<1249, 256, 0, stream>>>(
      features, pos_embed, abuf, queries, query_pos, aq,
      key_proj_w, bkey, query_proj_w, bq,
      A_log, dt_bias, dist_w1, dist_b1, dist_w2, bc_proj_w, dt_proj_w, wprep,
      yacc, flag);

  // 2. kp = abuf @ bkey : (4096 x 1034), K=256
  kp_gemm_kernel<<<dim3(64, 17), 256, 0, stream>>>(abuf, bkey, kp);

  // 3. conv + qproj GEMM (separate from dist: r9 merge crushed occupancy)
  convqp_kernel<<<4096 + 32, 256, 0, stream>>>(
      flag, kp, key_conv_w, key_conv_b, xact, aq, bq, qproj);

  // 4. dist (standalone, own regalloc)
  dist_kernel<<<BSZ_*LSEQ_/2, 256, 0, stream>>>(flag, anchors, key_pos, kp, xact,
                                                wprep, aw, carr);

  // 5. s1 group-LDS-staged
  s1m_kernel<<<dim3(8, NCHUNK_, BSZ_*NH_), 256, 0, stream>>>(aw, xact, send, ptot);

  // 6. s2
  s2_kernel<<<1024, 256, 0, stream>>>(qproj, ptot, send, h0buf, hbuf);

  // 7. s3 group-LDS-staged (control) + cast1
  s3cast_kernel<<<2048 + 512, 256, 0, stream>>>(
      flag, aw, carr, xact, h0buf, yacc,
      out_key_proj_w, bok, out_query_proj_w, boq, ffn_fc1_w, b1w, ffn_fc2_w, b2w);

  // 8. g + lnq
  glnq_kernel<<<4096 + 256, 256, 0, stream>>>(
      flag, yacc, xact, kp, Dvec, key_norm_w, gbuf,
      hbuf, query_norm_w, query_norm_b, lnq);

  // 9. out_feat GEMM + outq GEMM
  ofoq_kernel<<<256 + 16, 256, 0, stream>>>(
      flag, gbuf, bok, out_feat_f32, out_feat_bf16, features,
      lnq, boq, outqf, queries);

  // 10. fc1 + gelu with in-block FFN LN (lnf kernel removed)
  fc1g_kernel<<<dim3(4, 16), 256, 0, stream>>>(
      flag, outqf, ffn_norm_w, ffn_norm_b, b1w, ffn_fc1_b, ugbuf);

  // 11. fc2: out_q = outqf + ug @ b2w + b2
  fc2_kernel<<<16, 256, 0, stream>>>(flag, ugbuf, b2w, out_q, outqf, ffn_fc2_b);
}

// Round 11
// 374.323 us; speedup vs baseline: 1.1696x; 1.0159x over previous
//
#include <hip/hip_runtime.h>

typedef unsigned short u16;
typedef __bf16 bf16x8 __attribute__((ext_vector_type(8)));
typedef u16 u16x8 __attribute__((ext_vector_type(8)));
typedef u16 u16x2 __attribute__((ext_vector_type(2)));
typedef float f32x4 __attribute__((ext_vector_type(4)));
typedef float f32x2 __attribute__((ext_vector_type(2)));

#define BSZ_ 2
#define NQ_ 128
#define LSEQ_ 2048
#define DM_ 256
#define DI_ 512
#define NH_ 8
#define HD_ 64
#define DKEY_ 1034
#define DCV_ 514
#define NCHUNK_ 16
#define CT_ 128   // chunk length

__device__ __forceinline__ float bf2f(u16 u) {
  unsigned v = ((unsigned)u) << 16;
  return __builtin_bit_cast(float, v);
}
__device__ __forceinline__ u16 f2bf(float f) {
  unsigned u = __builtin_bit_cast(unsigned, f);
  u += 0x7fffu + ((u >> 16) & 1u);
  return (u16)(u >> 16);
}
__device__ __forceinline__ float sigmoidf_(float x) { return 1.f / (1.f + expf(-x)); }
__device__ __forceinline__ float softplusf_(float x) {
  return (x > 20.f) ? x : log1pf(expf(x));
}

template<bool F32>
__device__ __forceinline__ float ldi(const void* p, size_t i) {
  return F32 ? ((const float*)p)[i] : bf2f(((const u16*)p)[i]);
}
template<bool F32>
__device__ __forceinline__ void sto(void* p, size_t i, float v) {
  if (F32) ((float*)p)[i] = v;
  else ((u16*)p)[i] = f2bf(v);
}

// per-wave dtype detection (all waves read same 64 u16s -> uniform result)
__device__ __forceinline__ bool detect_f32(const void* feat) {
  int lane = threadIdx.x & 63;
  float a = fabsf(bf2f(((const u16*)feat)[2*lane]));
  bool plaus = (a > 1e-6f) && (a < 1e6f);
  unsigned long long m = __ballot(plaus);
  return __popcll(m) < 32;   // true => fp32 storage
}

// ---------------- workspace layout (float units) ----------------
constexpr size_t SZ_KP    = (size_t)BSZ_*LSEQ_*DKEY_;
constexpr size_t SZ_XACT  = (size_t)BSZ_*LSEQ_*DCV_;
constexpr size_t SZ_AW    = (size_t)BSZ_*NH_*LSEQ_*NQ_*2;
constexpr size_t SZ_CARR  = (size_t)BSZ_*LSEQ_*NQ_;
constexpr size_t SZ_QPROJ = (size_t)BSZ_*NQ_*DI_;
constexpr size_t SZ_YACC  = (size_t)BSZ_*LSEQ_*DI_;
constexpr size_t SZ_SEND  = (size_t)BSZ_*NH_*2*NCHUNK_*NQ_*HD_;
constexpr size_t SZ_PTOT  = (size_t)BSZ_*NH_*2*NCHUNK_*NQ_;
constexpr size_t SZ_H0    = SZ_SEND;
constexpr size_t SZ_HB    = (size_t)BSZ_*NH_*2*NQ_*HD_;
constexpr size_t SZ_GBUF  = (size_t)BSZ_*LSEQ_*DI_/2;
constexpr size_t SZ_OUTQF = (size_t)BSZ_*NQ_*DM_;
constexpr size_t SZ_WPREP = 2048;

constexpr size_t OFF_KP    = 0;
constexpr size_t OFF_XACT  = OFF_KP + SZ_KP;
constexpr size_t OFF_AW    = OFF_XACT + SZ_XACT;
constexpr size_t OFF_CARR  = OFF_AW + SZ_AW;
constexpr size_t OFF_QPROJ = OFF_CARR + SZ_CARR;
constexpr size_t OFF_YACC  = OFF_QPROJ + SZ_QPROJ;
constexpr size_t OFF_SEND  = OFF_YACC + SZ_YACC;
constexpr size_t OFF_PTOT  = OFF_SEND + SZ_SEND;
constexpr size_t OFF_H0    = OFF_PTOT + SZ_PTOT;
constexpr size_t OFF_HB    = OFF_H0 + SZ_H0;
constexpr size_t OFF_GBUF  = OFF_HB + SZ_HB;
constexpr size_t OFF_OUTQF = OFF_GBUF + SZ_GBUF;
constexpr size_t OFF_WPREP = OFF_OUTQF + SZ_OUTQF;
constexpr size_t WS_FLOATS = OFF_WPREP + SZ_WPREP;

// FFN/outq scratch aliases into AW (dead after s3):
constexpr size_t OFF_UG  = OFF_AW;                         // 256x1024 bf16
constexpr size_t OFF_LNQ = OFF_UG + (size_t)256*1024/2;    // 256x512 bf16

// Transient bf16 cast buffers alias SEND (dead until s1 writes it):
constexpr size_t OFF_ABUF = OFF_SEND;                         // 4096x256 bf16
constexpr size_t OFF_AQ   = OFF_ABUF + (size_t)4096*256/2;
constexpr size_t OFF_BKEY = OFF_AQ + (size_t)256*256/2;
constexpr size_t OFF_BQ   = OFF_BKEY + (size_t)(256*1034+1)/2 + 1;
// Late bf16 weight casts alias SEND (dead after s2):
constexpr size_t OFF_BOK  = OFF_SEND;
constexpr size_t OFF_BOQ  = OFF_BOK + (size_t)512*256/2;
constexpr size_t OFF_B1W  = OFF_BOQ + (size_t)512*256/2;
constexpr size_t OFF_B2W  = OFF_B1W + (size_t)256*2048/2;

// wprep layout: [0..7] A=-exp(A_log); [8..15] dt_bias; [32..287] w1b; [288..1311] w2;
// [1312..1343] bc_proj; [1344..1471] dt_proj
template<bool F32>
__device__ void prep_body(const void* A_log, const void* dt_bias,
                          const void* w1, const void* b1, const void* w2,
                          const void* bcw, const void* dtw, float* wp) {
  int t = threadIdx.x;
  if (t < 8) {
    wp[t]     = -expf(ldi<F32>(A_log, t));
    wp[8 + t] = ldi<F32>(dt_bias, t);
  }
  if (t < 64) {
    wp[32 + t*4 + 0] = ldi<F32>(w1, 0*64 + t);
    wp[32 + t*4 + 1] = ldi<F32>(w1, 1*64 + t);
    wp[32 + t*4 + 2] = ldi<F32>(w1, 2*64 + t);
    wp[32 + t*4 + 3] = ldi<F32>(b1, t);
  }
  for (int i = t; i < 1024; i += 256) wp[288 + i] = ldi<F32>(w2, i);
  if (t < 32)  wp[1312 + t] = ldi<F32>(bcw, t);
  if (t < 128) wp[1344 + t] = ldi<F32>(dtw, t);
}

// cast helper: d[i] = bf16(s0[i] (+ s1_[i]))
__device__ __forceinline__ void cast_job(bool F32, const void* s0, const void* s1_,
                                         u16* d, size_t n, size_t base, size_t stride) {
  for (size_t i = base; i < n; i += stride) {
    float v = F32 ? ((const float*)s0)[i] : bf2f(((const u16*)s0)[i]);
    if (s1_) v += F32 ? ((const float*)s1_)[i] : bf2f(((const u16*)s1_)[i]);
    d[i] = f2bf(v);
  }
}

// ---------------- setup: yacc zero + cast0 + detect/prep (fused) ----------------
__global__ __launch_bounds__(256) void setup_kernel(
    const void* feat, const void* pe, u16* abuf,
    const void* q, const void* qp, u16* aq,
    const void* kw, u16* bkey, const void* qw, u16* bq,
    const void* A_log, const void* dt_bias, const void* w1, const void* b1,
    const void* w2, const void* bcw, const void* dtw, float* wp,
    float* yacc, int* flag)
{
  int bx = blockIdx.x, tid = threadIdx.x;
  if (bx < 512) {                       // yacc zero: 512 blocks x 4096 floats
    size_t base = (size_t)bx * 4096 + tid;
#pragma unroll
    for (int k = 0; k < 16; ++k) yacc[base + (size_t)k*256] = 0.f;
    return;
  }
  bool F32 = detect_f32(feat);
  if (bx < 1024) {                      // abuf = bf16(features + pos_embed)
    cast_job(F32, feat, pe, abuf, (size_t)4096*256,
             (size_t)(bx-512)*256 + tid, (size_t)512*256);
  } else if (bx < 1056) {               // aq = bf16(queries + query_pos)
    cast_job(F32, q, qp, aq, (size_t)256*256,
             (size_t)(bx-1024)*256 + tid, (size_t)32*256);
  } else if (bx < 1184) {               // bkey = bf16(key_proj_w)
    cast_job(F32, kw, nullptr, bkey, (size_t)256*1034,
             (size_t)(bx-1056)*256 + tid, (size_t)128*256);
  } else if (bx < 1248) {               // bq = bf16(query_proj_w)
    cast_job(F32, qw, nullptr, bq, (size_t)256*512,
             (size_t)(bx-1184)*256 + tid, (size_t)64*256);
  } else {                              // detect-store + prep
    if (tid == 0) *flag = F32 ? 1 : 0;
    if (F32) prep_body<true>(A_log, dt_bias, w1, b1, w2, bcw, dtw, wp);
    else     prep_body<false>(A_log, dt_bias, w1, b1, w2, bcw, dtw, wp);
  }
}

// ---------------- MFMA GEMM body (Bs padded to 42: bank-conflict-free) ----------
// BV: B-stage vector width. 2 = unconditional u16x8 (row stride 16B-aligned,
// tiles always full: N in {256,512,1024,2048}); 1 = guarded 4x u16x2
// (4B-aligned only, N=1034); 0 = scalar fallback.
template<int A_MODE, int B_MODE, int BV, int OUT_EEXT, int RES_EXT, int RES_F32, int BIAS, bool F32>
__device__ void gemm_body(int bm, int bn,
                          const void* A0, const void* A1, const void* Bw,
                          float* Cf, void* Cext, const void* ResE,
                          const float* ResF, const void* Bias,
                          int M, int N, int K) {
  __shared__ u16 As[64][40];
  __shared__ u16 Bs[64][42];
  int tid = threadIdx.x;
  int w = tid >> 6, lane = tid & 63;
  f32x4 acc[4];
#pragma unroll
  for (int j = 0; j < 4; ++j) acc[j] = (f32x4){0.f, 0.f, 0.f, 0.f};

  int arow = tid >> 2, aseg = (tid & 3) * 8;
  int bkl = tid >> 3, bns = (tid & 7) * 8;

  for (int k0 = 0; k0 < K; k0 += 32) {
    {
      size_t abase = (size_t)(bm + arow) * K + k0 + aseg;
      u16x8 tv;
      if (A_MODE == 0) {
#pragma unroll
        for (int i = 0; i < 8; ++i)
          tv[i] = f2bf(ldi<F32>(A0, abase + i) + ldi<F32>(A1, abase + i));
      } else {
        tv = *(const u16x8*)((const u16*)A0 + abase);   // 16B-aligned for all uses
      }
      *(u16x8*)&As[arow][aseg] = tv;
    }
    {
      size_t bbase = (size_t)(k0 + bkl) * N + bn + bns;
      if (BV == 2) {
        u16x8 bv8 = *(const u16x8*)((const u16*)Bw + bbase);
#pragma unroll
        for (int i = 0; i < 8; ++i) Bs[bns + i][bkl] = bv8[i];
      } else if (BV == 1 && bn + bns + 8 <= N) {
        const u16* bp = (const u16*)Bw + bbase;
#pragma unroll
        for (int i2 = 0; i2 < 4; ++i2) {
          u16x2 v2 = *(const u16x2*)(bp + i2*2);
          Bs[bns + i2*2][bkl]     = v2[0];
          Bs[bns + i2*2 + 1][bkl] = v2[1];
        }
      } else {
#pragma unroll
        for (int i = 0; i < 8; ++i) {
          u16 v;
          if (bn + bns + i < N) {
            if (B_MODE == 1) v = ((const u16*)Bw)[bbase + i];
            else             v = f2bf(ldi<F32>(Bw, bbase + i));
          } else v = (u16)0;
          Bs[bns + i][bkl] = v;
        }
      }
    }
    __syncthreads();
    int mrow = w * 16 + (lane & 15);
    int kq = (lane >> 4) * 8;
    bf16x8 af = __builtin_bit_cast(bf16x8, *(const u16x8*)&As[mrow][kq]);
#pragma unroll
    for (int j = 0; j < 4; ++j) {
      bf16x8 bfv = __builtin_bit_cast(bf16x8, *(const u16x8*)&Bs[j*16 + (lane & 15)][kq]);
      acc[j] = __builtin_amdgcn_mfma_f32_16x16x32_bf16(af, bfv, acc[j], 0, 0, 0);
    }
    __syncthreads();
  }
  int col0 = lane & 15, rbase = (lane >> 4) * 4;
#pragma unroll
  for (int j = 0; j < 4; ++j) {
#pragma unroll
    for (int r = 0; r < 4; ++r) {
      int row = bm + w * 16 + rbase + r;
      int col = bn + j * 16 + col0;
      if (col < N) {
        size_t idx = (size_t)row * N + col;
        float v = acc[j][r];
        if (BIAS)     v += ldi<F32>(Bias, col);
        if (RES_EXT)  v += ldi<F32>(ResE, idx);
        if (RES_F32)  v += ResF[idx];
        if (OUT_EEXT) sto<F32>(Cext, idx, v);
        else          Cf[idx] = v;
      }
    }
  }
}

// kp = abuf @ bkey (all-internal bf16, fp32 out); N=1034 -> BV=1 (4B-aligned)
__global__ __launch_bounds__(256) void kp_gemm_kernel(
    const u16* abuf, const u16* bkey, float* kp) {
  gemm_body<1,1,1,0,0,0,0,false>(blockIdx.x*64, blockIdx.y*64, abuf, nullptr, bkey,
                                 kp, nullptr, nullptr, nullptr, nullptr,
                                 4096, DKEY_, DM_);
}

// fc2: out_q = outqf + ug @ b2w + b2
template<bool F32>
__device__ void fc2_body(const u16* ug, const u16* b2w, void* out_q,
                         const float* outqf, const void* b2) {
  gemm_body<1,1,2,1,0,1,1,F32>((blockIdx.x&3)*64, (blockIdx.x>>2)*64, ug, nullptr,
                               b2w, nullptr, out_q, nullptr, outqf, b2,
                               BSZ_*NQ_, DM_, 1024);
}
__global__ __launch_bounds__(256) void fc2_kernel(
    const int* fl, const u16* ug, const u16* b2w, void* out_q,
    const float* outqf, const void* b2) {
  if (*fl) fc2_body<true>(ug, b2w, out_q, outqf, b2);
  else     fc2_body<false>(ug, b2w, out_q, outqf, b2);
}

// ---------------- conv + qproj GEMM (fused, independent blocks) ----------------
template<bool F32>
__device__ void conv_body(const float* kp, const void* cw, const void* cb,
                          float* xact) {
  int row = blockIdx.x;
  int l = row & (LSEQ_ - 1);
  for (int ch = threadIdx.x; ch < DCV_; ch += 256) {
    float acc = ldi<F32>(cb, ch);
#pragma unroll
    for (int k = 0; k < 4; ++k) {
      int ll = l - 3 + k;
      if (ll >= 0)
        acc = fmaf(ldi<F32>(cw, ch*4 + k), kp[(size_t)(row - 3 + k)*DKEY_ + DI_ + ch], acc);
    }
    xact[(size_t)row*DCV_ + ch] = acc * sigmoidf_(acc);
  }
}
__global__ __launch_bounds__(256) void convqp_kernel(
    const int* fl, const float* kp, const void* cw, const void* cb, float* xact,
    const u16* aq, const u16* bq, float* qproj)
{
  int bx = blockIdx.x;
  if (bx < 4096) {
    if (*fl) conv_body<true>(kp, cw, cb, xact);
    else     conv_body<false>(kp, cw, cb, xact);
  } else {
    int i = bx - 4096;   // 32 blocks: M=256 (4 tiles) x N=512 (8 tiles)
    gemm_body<1,1,2,0,0,0,0,false>((i&3)*64, (i>>2)*64, aq, nullptr, bq,
                                   qproj, nullptr, nullptr, nullptr, nullptr,
                                   BSZ_*NQ_, DI_, DM_);
  }
}

// ---------------- dist MLP -> a, w, c (standalone, own regalloc) ---------------
template<bool F32>
__device__ void dist_body(const void* anchors, const void* key_pos,
                          const float* kp, const float* xact, const float* wp,
                          float* aw, float* carr) {
  int tid = threadIdx.x;
  int n = tid & 127;
  int idx = blockIdx.x;
  int b = idx >> 10;
  int l = ((idx & 1023) << 1) | (tid >> 7);
  size_t row = (size_t)b * LSEQ_ + l;

  float enc0, enc1, enc2;
  {
    float e[3];
#pragma unroll
    for (int d = 0; d < 3; ++d) {
      float delta = ldi<F32>(anchors, (b*NQ_ + n)*3 + d) - ldi<F32>(key_pos, row*3 + d);
      float s = delta < 0.f ? -1.f : 1.f;
      e[d] = s * log2f(fabsf(delta) * 20.f + 1.f) * (1.f/12.f);
    }
    enc0 = e[0]; enc1 = e[1]; enc2 = e[2];
  }
  float feat[16];
#pragma unroll
  for (int f = 0; f < 16; ++f) feat[f] = 0.f;
  for (int j = 0; j < 64; ++j) {
    float w0 = wp[32 + j*4], w1v = wp[33 + j*4], w2v = wp[34 + j*4], bb = wp[35 + j*4];
    float hj = fmaxf(fmaf(enc0, w0, fmaf(enc1, w1v, fmaf(enc2, w2v, bb))), 0.f);
#pragma unroll
    for (int f = 0; f < 16; ++f) feat[f] = fmaf(hj, wp[288 + j*16 + f], feat[f]);
  }
  float bc0 = 0.f, bc1 = 0.f;
#pragma unroll
  for (int f = 0; f < 16; ++f) {
    bc0 = fmaf(feat[f], wp[1312 + f*2], bc0);
    bc1 = fmaf(feat[f], wp[1313 + f*2], bc1);
  }
  float bb_ = xact[row*DCV_ + DI_];
  float cb_ = xact[row*DCV_ + DI_ + 1];
  float Bs = bc0 + bb_, Cs = bc1 + cb_;
  carr[row*NQ_ + n] = Cs;

  float dtb[8];
#pragma unroll
  for (int h = 0; h < 8; ++h) dtb[h] = 0.f;
#pragma unroll
  for (int f = 0; f < 16; ++f)
#pragma unroll
    for (int h = 0; h < 8; ++h) dtb[h] = fmaf(feat[f], wp[1344 + f*8 + h], dtb[h]);

#pragma unroll
  for (int h = 0; h < 8; ++h) {
    float xln = dtb[h] + kp[row*DKEY_ + (DI_*2 + 2) + h] + wp[8 + h];
    float dtv = softplusf_(xln);
    float a = expf(dtv * wp[h]);
    float wv = dtv * Bs;
    size_t o = (((size_t)(b*NH_ + h)*LSEQ_ + l)*NQ_ + n)*2;
    aw[o] = a;
    aw[o + 1] = wv;
  }
}
__global__ __launch_bounds__(256) void dist_kernel(
    const int* fl, const void* anchors, const void* key_pos, const float* kp,
    const float* xact, const float* wp, float* aw, float* carr) {
  if (*fl) dist_body<true>(anchors, key_pos, kp, xact, wp, aw, carr);
  else     dist_body<false>(anchors, key_pos, kp, xact, wp, aw, carr);
}

// ---------------- scan phase 1: group-LDS-staged + PACKED FP32 -----------------
// a/w de-interleaved at stage time (awa/aww); h-state held as f32x2 pairs so the
// inner step compiles to v_pk_mul/v_pk_fma (2-wide f32 VOP3P on CDNA3/4):
// 16 scalar VALU/step -> 8 packed. Summation order unchanged (independent lanes).
__global__ __launch_bounds__(256) void s1m_kernel(
    const float* __restrict__ aw, const float* __restrict__ xact,
    float* __restrict__ send, float* __restrict__ ptot)
{
  __shared__ float awa[2][8][16];   // 1 KB
  __shared__ float aww[2][8][16];   // 1 KB
  __shared__ float xl [2][8][64];   // 4 KB
  int tid = threadIdx.x;
  int hd = tid & 63;
  int w = __builtin_amdgcn_readfirstlane(tid >> 6);
  int ns = blockIdx.x, q = blockIdx.y, z = blockIdx.z;   // z = b*NH_ + h
  int h = z & 7, b = z >> 3;
  int n0 = __builtin_amdgcn_readfirstlane(ns*16 + w*4);

  f32x2 hf01 = {0.f,0.f}, hf23 = {0.f,0.f};
  f32x2 hb01 = {0.f,0.f}, hb23 = {0.f,0.f};
  f32x2 pr01 = {1.f,1.f}, pr23 = {1.f,1.f};

  // stage thread mapping: s8 = step-in-group (0..7), j = 0..31
  int s8 = tid >> 5, j = tid & 31;
  int t0 = q*CT_;
  const float* awg = aw + (size_t)z*LSEQ_*(NQ_*2)
                     + (size_t)(t0 + s8)*(NQ_*2) + ns*32 + (j & 15)*2;
  const float* xg  = xact + ((size_t)(b*LSEQ_) + t0 + s8)*DCV_ + (h<<6) + j*2;
  const long awgstep = 8L*(NQ_*2);
  const long xgstep  = 8L*DCV_;

  // prologue: stage group 0 (threads j<16 stage the 16 (a,w) pairs per step)
  {
    f32x2 pa = *(const f32x2*)awg;
    f32x2 px = *(const f32x2*)xg;
    awg += awgstep; xg += xgstep;
    if (j < 16) { awa[0][s8][j] = pa[0]; aww[0][s8][j] = pa[1]; }
    *(f32x2*)&xl[0][s8][j*2] = px;
  }
  asm volatile("s_waitcnt lgkmcnt(0)" ::: "memory");
  __builtin_amdgcn_s_barrier();

  int p = 0;
  f32x2 sa; f32x2 sx;
  for (int g = 0; g < 16; ++g) {
    if (g < 15) {
      sa = *(const f32x2*)awg; sx = *(const f32x2*)xg;
      awg += awgstep; xg += xgstep;
    }
#pragma unroll
    for (int s = 0; s < 8; ++s) {
      const f32x2* Aa = (const f32x2*)&awa[p][s][w*4];
      const f32x2* Aw = (const f32x2*)&aww[p][s][w*4];
      float xv = xl[p][s][hd];
      f32x2 xv2 = {xv, xv};
      f32x2 wx0 = Aw[0] * xv2;
      f32x2 wx1 = Aw[1] * xv2;
      hf01 = hf01 * Aa[0] + wx0;
      hf23 = hf23 * Aa[1] + wx1;
      hb01 = pr01 * wx0 + hb01;
      hb23 = pr23 * wx1 + hb23;
      pr01 = pr01 * Aa[0];
      pr23 = pr23 * Aa[1];
    }
    if (g < 15) {
      if (j < 16) { awa[p^1][s8][j] = sa[0]; aww[p^1][s8][j] = sa[1]; }
      *(f32x2*)&xl[p^1][s8][j*2] = sx;
    }
    asm volatile("s_waitcnt lgkmcnt(0)" ::: "memory");
    __builtin_amdgcn_s_barrier();
    p ^= 1;
  }

  float hf[4] = {hf01[0], hf01[1], hf23[0], hf23[1]};
  float hb[4] = {hb01[0], hb01[1], hb23[0], hb23[1]};
  float pr[4] = {pr01[0], pr01[1], pr23[0], pr23[1]};
  size_t cbf = (size_t)((z*2 + 0)*NCHUNK_ + q);
  size_t cbb = (size_t)((z*2 + 1)*NCHUNK_ + (NCHUNK_ - 1 - q));
#pragma unroll
  for (int i = 0; i < 4; ++i) {
    send[cbf*(NQ_*HD_) + (size_t)(n0 + i)*HD_ + hd] = hf[i];
    send[cbb*(NQ_*HD_) + (size_t)(n0 + i)*HD_ + hd] = hb[i];
  }
  if (hd == 0) {
#pragma unroll
    for (int i = 0; i < 4; ++i) {
      ptot[cbf*NQ_ + n0 + i] = pr[i];
      ptot[cbb*NQ_ + n0 + i] = pr[i];
    }
  }
}

// ---------------- scan phase 2 ----------------
__global__ __launch_bounds__(256) void s2_kernel(
    const float* __restrict__ qproj, const float* __restrict__ ptot,
    const float* __restrict__ send, float* __restrict__ h0buf,
    float* __restrict__ hbuf)
{
  int g = blockIdx.x*256 + threadIdx.x;
  int hd = g & 63;
  int n = (g >> 6) & 127;
  int dir = (g >> 13) & 1;
  int h = (g >> 14) & 7;
  int b = g >> 17;
  float hcur = qproj[((size_t)(b*NQ_ + n))*DI_ + h*HD_ + hd];
  size_t base = (size_t)((b*NH_ + h)*2 + dir) * NCHUNK_;
  for (int q = 0; q < NCHUNK_; ++q) {
    size_t cb = base + q;
    h0buf[cb*(NQ_*HD_) + (size_t)n*HD_ + hd] = hcur;
    hcur = fmaf(hcur, ptot[cb*NQ_ + n], send[cb*(NQ_*HD_) + (size_t)n*HD_ + hd]);
  }
  hbuf[((size_t)((b*NH_ + h)*2 + dir))*(NQ_*HD_) + (size_t)n*HD_ + hd] = hcur;
}

// ---------------- scan phase 3: group-LDS-staged + PACKED FP32 + cast1 ---------
// Same structure as the proven r6 kernel; a/w de-interleaved (awa/aww, same
// total LDS = 18432B), h-state in f32x2 pairs -> v_pk_fma_f32: 24 scalar
// VALU/step -> 12 packed. ys pair-summation order identical to prior ya/yb.
template<bool F32>
__device__ void cast1_part(const void* okw, u16* bok, const void* oqw, u16* boq,
                           const void* w1, u16* b1w, const void* w2, u16* b2w) {
  int i = blockIdx.x - 2048;
  int job = i >> 7, bj = i & 127;
  size_t base = (size_t)bj*256 + threadIdx.x, stride = (size_t)128*256;
  switch (job) {
    case 0: cast_job(F32, okw, nullptr, bok, (size_t)512*256, base, stride); break;
    case 1: cast_job(F32, oqw, nullptr, boq, (size_t)512*256, base, stride); break;
    case 2: cast_job(F32, w1, nullptr, b1w, (size_t)256*2048, base, stride); break;
    default: cast_job(F32, w2, nullptr, b2w, (size_t)1024*256, base, stride); break;
  }
}
__global__ __launch_bounds__(256) void s3cast_kernel(
    const int* fl, const float* __restrict__ aw, const float* __restrict__ carr,
    const float* __restrict__ xact, const float* __restrict__ h0buf,
    float* __restrict__ yacc,
    const void* okw, u16* bok, const void* oqw, u16* boq,
    const void* w1, u16* b1w, const void* w2, u16* b2w)
{
  int bx = blockIdx.x;
  if (bx >= 2048) {
    if (*fl) cast1_part<true>(okw, bok, oqw, boq, w1, b1w, w2, b2w);
    else     cast1_part<false>(okw, bok, oqw, boq, w1, b1w, w2, b2w);
    return;
  }
  __shared__ float awa[2][8][32];   // 2 KB
  __shared__ float aww[2][8][32];   // 2 KB
  __shared__ float ctl[2][8][32];   // 2 KB
  __shared__ float xl [2][8][64];   // 4 KB
  __shared__ float yl [8][4][64];   // 8 KB  -> total 18 KB (same as r6)

  int tid = threadIdx.x;
  int hd = tid & 63;
  int w = __builtin_amdgcn_readfirstlane(tid >> 6);
  int ns = bx & 3, q = (bx >> 2) & 15, zz = bx >> 6;
  int dir = zz & 1, h = (zz >> 1) & 7, b = zz >> 4;
  int z = b*NH_ + h;
  int n0 = ns*32 + w*8;

  int tbase = dir ? (LSEQ_ - 1 - q*CT_) : (q*CT_);
  int tstep = dir ? -1 : 1;

  // stage thread mapping: s8 = step-in-group, j = 0..31 (pair for n=ns*32+j)
  int s8 = tid >> 5, j = tid & 31;
  const float* awg = aw + (size_t)z*LSEQ_*(NQ_*2)
                     + (size_t)(tbase + tstep*s8)*(NQ_*2) + ns*64 + j*2;
  const float* ctg = carr + ((size_t)(b*LSEQ_) + tbase + tstep*s8)*NQ_ + ns*32 + j;
  const float* xg  = xact + ((size_t)(b*LSEQ_) + tbase + tstep*s8)*DCV_ + (h<<6) + j*2;
  long awgstep = (long)tstep*8*(NQ_*2);
  long ctgstep = (long)tstep*8*NQ_;
  long xgstep  = (long)tstep*8*DCV_;

  // prologue: issue stage(group 0) loads first (deep), then h0 state loads
  f32x2 pa = *(const f32x2*)awg;
  float pc = *ctg;
  f32x2 px = *(const f32x2*)xg;
  awg += awgstep; ctg += ctgstep; xg += xgstep;

  f32x2 h01, h23, h45, h67;
  {
    size_t cb = (size_t)((z*2 + dir)*NCHUNK_ + q);
    const float* hp = h0buf + cb*(NQ_*HD_) + (size_t)n0*HD_ + hd;
    h01 = (f32x2){hp[0*HD_], hp[1*HD_]};
    h23 = (f32x2){hp[2*HD_], hp[3*HD_]};
    h45 = (f32x2){hp[4*HD_], hp[5*HD_]};
    h67 = (f32x2){hp[6*HD_], hp[7*HD_]};
  }
  awa[0][s8][j] = pa[0];
  aww[0][s8][j] = pa[1];
  ctl[0][s8][j] = pc;
  *(f32x2*)&xl[0][s8][j*2] = px;
  asm volatile("s_waitcnt lgkmcnt(0)" ::: "memory");
  __builtin_amdgcn_s_barrier();

  float* yrow = yacc + ((size_t)(b*LSEQ_) + tbase)*DI_ + (h << 6) + hd;
  long ystep = (long)tstep * DI_;

  int p = 0;
  f32x2 sa; float sc; f32x2 sx;
  for (int g = 0; g < 16; ++g) {
    if (g < 15) {
      sa = *(const f32x2*)awg; sc = *ctg; sx = *(const f32x2*)xg;
      awg += awgstep; ctg += ctgstep; xg += xgstep;
    }
    if (g > 0) {
#pragma unroll
      for (int r = 0; r < 2; ++r) {
        int s = w + r*4;
        float yv = yl[s][0][hd] + yl[s][1][hd] + yl[s][2][hd] + yl[s][3][hd];
        atomicAdd(yrow + (long)((g-1)*8 + s)*ystep, 0.5f * yv);
      }
    }
    asm volatile("s_waitcnt lgkmcnt(0)" ::: "memory");
    __builtin_amdgcn_s_barrier();           // yl reads done before overwrite
#pragma unroll
    for (int s = 0; s < 8; ++s) {
      const f32x2* Aa = (const f32x2*)&awa[p][s][w*8];
      const f32x2* Aw = (const f32x2*)&aww[p][s][w*8];
      const f32x2* Cc = (const f32x2*)&ctl[p][s][w*8];
      float xv = xl[p][s][hd];
      f32x2 xv2 = {xv, xv};
      f32x2 wx, ys2;
      wx = Aw[0] * xv2; h01 = h01 * Aa[0] + wx; ys2 = h01 * Cc[0];
      wx = Aw[1] * xv2; h23 = h23 * Aa[1] + wx; ys2 += h23 * Cc[1];
      wx = Aw[2] * xv2; h45 = h45 * Aa[2] + wx; ys2 += h45 * Cc[2];
      wx = Aw[3] * xv2; h67 = h67 * Aa[3] + wx; ys2 += h67 * Cc[3];
      yl[s][w][hd] = ys2[0] + ys2[1];
    }
    if (g < 15) {
      awa[p^1][s8][j] = sa[0];
      aww[p^1][s8][j] = sa[1];
      ctl[p^1][s8][j] = sc;
      *(f32x2*)&xl[p^1][s8][j*2] = sx;
    }
    asm volatile("s_waitcnt lgkmcnt(0)" ::: "memory");
    __builtin_amdgcn_s_barrier();           // staged buffer ready for g+1
    p ^= 1;
  }
#pragma unroll
  for (int r = 0; r < 2; ++r) {
    int s = w + r*4;
    float yv = yl[s][0][hd] + yl[s][1][hd] + yl[s][2][hd] + yl[s][3][hd];
    atomicAdd(yrow + (long)(15*8 + s)*ystep, 0.5f * yv);
  }
}

// ---------------- block reduction helper ----------------
__device__ __forceinline__ float block_sum256(float v, float* red) {
#pragma unroll
  for (int off = 32; off; off >>= 1) v += __shfl_xor(v, off, 64);
  int wv = threadIdx.x >> 6;
  if ((threadIdx.x & 63) == 0) red[wv] = v;
  __syncthreads();
  float t = red[0] + red[1] + red[2] + red[3];
  __syncthreads();
  return t;
}

// ---------------- g (gated RMSNorm) + lnq (fused) ----------------
template<bool F32>
__device__ void g_body(const float* yacc, const float* xact, const float* kp,
                       const void* Dv, const void* knw, u16* gbuf) {
  int row = blockIdx.x, tid = threadIdx.x;
  __shared__ float red[4];
  float gg[2];
  float ss = 0.f;
#pragma unroll
  for (int ii = 0; ii < 2; ++ii) {
    int ch = tid + ii*256;
    float yv = yacc[(size_t)row*DI_ + ch];
    float xv = xact[(size_t)row*DCV_ + ch];
    float zv = kp[(size_t)row*DKEY_ + ch];
    float Dh = ldi<F32>(Dv, ch >> 6);
    float yf = yv + 2.f * Dh * xv;
    float g = yf * (zv * sigmoidf_(zv));
    gg[ii] = g;
    ss += g * g;
  }
  float tot = block_sum256(ss, red);
  float r = rsqrtf(tot / (float)DI_ + 1e-5f);
#pragma unroll
  for (int ii = 0; ii < 2; ++ii) {
    int ch = tid + ii*256;
    gbuf[(size_t)row*DI_ + ch] = f2bf(gg[ii] * r * ldi<F32>(knw, ch));
  }
}
template<bool F32>
__device__ void lnq_body(const float* hbuf, const void* qnw, const void* qnb,
                         u16* lnq) {
  int row = blockIdx.x - 4096;
  int b = row >> 7, n = row & 127;
  int tid = threadIdx.x;
  __shared__ float red[4];
  float hv[2];
  float s1 = 0.f, s2 = 0.f;
#pragma unroll
  for (int ii = 0; ii < 2; ++ii) {
    int ch = tid + ii*256;
    int h = ch >> 6, hd = ch & 63;
    size_t base = ((size_t)((b*NH_ + h)*2))*(NQ_*HD_) + (size_t)n*HD_ + hd;
    float v = 0.5f * (hbuf[base] + hbuf[base + (size_t)NQ_*HD_]);
    hv[ii] = v;
    s1 += v;
    s2 += v * v;
  }
  s1 = block_sum256(s1, red);
  s2 = block_sum256(s2, red);
  float mean = s1 / (float)DI_;
  float var = fmaxf(s2 / (float)DI_ - mean * mean, 0.f);
  float rstd = rsqrtf(var + 1e-5f);
#pragma unroll
  for (int ii = 0; ii < 2; ++ii) {
    int ch = tid + ii*256;
    lnq[(size_t)row*DI_ + ch] =
        f2bf((hv[ii] - mean) * rstd * ldi<F32>(qnw, ch) + ldi<F32>(qnb, ch));
  }
}
__global__ __launch_bounds__(256) void glnq_kernel(
    const int* fl, const float* yacc, const float* xact, const float* kp,
    const void* Dv, const void* knw, u16* gbuf,
    const float* hbuf, const void* qnw, const void* qnb, u16* lnq)
{
  if (blockIdx.x < 4096) {
    if (*fl) g_body<true>(yacc, xact, kp, Dv, knw, gbuf);
    else     g_body<false>(yacc, xact, kp, Dv, knw, gbuf);
  } else {
    if (*fl) lnq_body<true>(hbuf, qnw, qnb, lnq);
    else     lnq_body<false>(hbuf, qnw, qnb, lnq);
  }
}

// ---------------- out_feat GEMM + outq GEMM (fused) ----------------
template<bool F32>
__device__ void ofoq_body(const u16* gbuf, const u16* bok, void* out_feat,
                          const void* features, const u16* lnq, const u16* boq,
                          float* outqf, const void* queries) {
  int bx = blockIdx.x;
  if (bx < 256) {   // out_feat: M=4096 (64 tiles) x N=256 (4 tiles), K=512
    gemm_body<1,1,2,1,1,0,0,F32>((bx>>2)*64, (bx&3)*64, gbuf, nullptr, bok,
                                 nullptr, out_feat, features, nullptr, nullptr,
                                 4096, DM_, DI_);
  } else {          // outq: M=256 (4) x N=256 (4), K=512
    int i = bx - 256;
    gemm_body<1,1,2,0,1,0,0,F32>((i&3)*64, (i>>2)*64, lnq, nullptr, boq,
                                 outqf, nullptr, queries, nullptr, nullptr,
                                 BSZ_*NQ_, DM_, DI_);
  }
}
__global__ __launch_bounds__(256) void ofoq_kernel(
    const int* fl, const u16* gbuf, const u16* bok,
    void* out_feat_f32, void* out_feat_bf16, const void* features,
    const u16* lnq, const u16* boq, float* outqf, const void* queries) {
  if (*fl) ofoq_body<true>(gbuf, bok, out_feat_f32, features, lnq, boq, outqf, queries);
  else     ofoq_body<false>(gbuf, bok, out_feat_bf16, features, lnq, boq, outqf, queries);
}

// ---------------- fc1 + gelu, with IN-BLOCK FFN LayerNorm (lnf kernel removed) --
template<bool F32>
__device__ void fc1g_body(const float* outqf, const void* fnw, const void* fnb,
                          const u16* b1w, const void* b1, u16* ug) {
  __shared__ u16 Asf[64][264];   // 33 KB
  __shared__ u16 BsA[64][42];
  __shared__ u16 BsV[64][42];
  __shared__ float red1[64][4];
  __shared__ float red2[64][4];
  int tid = threadIdx.x;
  int w = tid >> 6, lane = tid & 63;
  int bm = blockIdx.x * 64, bn = blockIdx.y * 64;   // bn in [0,1024)

  // ---- in-block LN of outqf rows [bm, bm+64) ----
  {
    int r = tid >> 2, qt = tid & 3;
    const float* src = outqf + (size_t)(bm + r)*DM_ + qt*64;
    float v[64];
    float s1 = 0.f, s2 = 0.f;
#pragma unroll
    for (int i = 0; i < 64; ++i) { v[i] = src[i]; s1 += v[i]; s2 += v[i]*v[i]; }
    red1[r][qt] = s1; red2[r][qt] = s2;
    __syncthreads();
    float t1 = red1[r][0] + red1[r][1] + red1[r][2] + red1[r][3];
    float t2 = red2[r][0] + red2[r][1] + red2[r][2] + red2[r][3];
    float mean = t1 / (float)DM_;
    float var = fmaxf(t2 / (float)DM_ - mean * mean, 0.f);
    float rstd = rsqrtf(var + 1e-5f);
#pragma unroll
    for (int i = 0; i < 64; ++i) {
      int col = qt*64 + i;
      Asf[r][col] = f2bf((v[i] - mean) * rstd * ldi<F32>(fnw, col)
                         + ldi<F32>(fnb, col));
    }
    __syncthreads();
  }

  f32x4 accA[4], accV[4];
#pragma unroll
  for (int j = 0; j < 4; ++j) {
    accA[j] = (f32x4){0.f, 0.f, 0.f, 0.f};
    accV[j] = (f32x4){0.f, 0.f, 0.f, 0.f};
  }
  int bkl = tid >> 3, bns = (tid & 7) * 8;

  for (int k0 = 0; k0 < DM_; k0 += 32) {
    {
      size_t bbase = (size_t)(k0 + bkl) * 2048 + bn + bns;
      u16x8 ba8 = *(const u16x8*)(b1w + bbase);          // 16B-aligned
      u16x8 bv8 = *(const u16x8*)(b1w + bbase + 1024);
#pragma unroll
      for (int i = 0; i < 8; ++i) {
        BsA[bns + i][bkl] = ba8[i];
        BsV[bns + i][bkl] = bv8[i];
      }
    }
    __syncthreads();
    int mrow = w * 16 + (lane & 15);
    int kq = (lane >> 4) * 8;
    bf16x8 af = __builtin_bit_cast(bf16x8, *(const u16x8*)&Asf[mrow][k0 + kq]);
#pragma unroll
    for (int j = 0; j < 4; ++j) {
      bf16x8 ba = __builtin_bit_cast(bf16x8, *(const u16x8*)&BsA[j*16 + (lane & 15)][kq]);
      bf16x8 bv = __builtin_bit_cast(bf16x8, *(const u16x8*)&BsV[j*16 + (lane & 15)][kq]);
      accA[j] = __builtin_amdgcn_mfma_f32_16x16x32_bf16(af, ba, accA[j], 0, 0, 0);
      accV[j] = __builtin_amdgcn_mfma_f32_16x16x32_bf16(af, bv, accV[j], 0, 0, 0);
    }
    __syncthreads();
  }
  int col0 = lane & 15, rbase = (lane >> 4) * 4;
#pragma unroll
  for (int j = 0; j < 4; ++j) {
#pragma unroll
    for (int r = 0; r < 4; ++r) {
      int row = bm + w * 16 + rbase + r;
      int col = bn + j * 16 + col0;
      float a = accA[j][r] + ldi<F32>(b1, col);
      float v = accV[j][r] + ldi<F32>(b1, col + 1024);
      float ge = 0.5f * a * (1.f + erff(a * 0.70710678118f));
      ug[(size_t)row*1024 + col] = f2bf(ge * v);
    }
  }
}
__global__ __launch_bounds__(256) void fc1g_kernel(
    const int* fl, const float* outqf, const void* fnw, const void* fnb,
    const u16* b1w, const void* b1, u16* ug) {
  if (*fl) fc1g_body<true>(outqf, fnw, fnb, b1w, b1, ug);
  else     fc1g_body<false>(outqf, fnw, fnb, b1w, b1, ug);
}

// ---------------- launch ----------------
extern "C" void kernel_launch(void* const* d_in, const int* in_sizes, int n_in,
                              void* d_out, int out_size, void* d_ws, size_t ws_size,
                              hipStream_t stream) {
  const void* queries        = d_in[0];
  const void* anchors        = d_in[1];
  const void* features       = d_in[2];
  const void* pos_embed      = d_in[3];
  const void* key_pos        = d_in[4];
  const void* query_pos      = d_in[5];
  const void* key_proj_w     = d_in[6];
  const void* key_conv_w     = d_in[7];
  const void* key_conv_b     = d_in[8];
  const void* query_proj_w   = d_in[9];
  const void* dist_w1        = d_in[10];
  const void* dist_b1        = d_in[11];
  const void* dist_w2        = d_in[12];
  const void* bc_proj_w      = d_in[13];
  const void* dt_proj_w      = d_in[14];
  const void* dt_bias        = d_in[15];
  const void* A_log          = d_in[16];
  const void* Dvec           = d_in[17];
  const void* key_norm_w     = d_in[18];
  const void* out_key_proj_w = d_in[19];
  const void* query_norm_w   = d_in[20];
  const void* query_norm_b   = d_in[21];
  const void* out_query_proj_w = d_in[22];
  const void* ffn_norm_w     = d_in[23];
  const void* ffn_norm_b     = d_in[24];
  const void* ffn_fc1_w      = d_in[25];
  const void* ffn_fc1_b      = d_in[26];
  const void* ffn_fc2_w      = d_in[27];
  const void* ffn_fc2_b      = d_in[28];

  if (ws_size < WS_FLOATS * sizeof(float)) return;

  float* ws    = (float*)d_ws;
  float* kp    = ws + OFF_KP;
  float* xact  = ws + OFF_XACT;
  float* aw    = ws + OFF_AW;
  float* carr  = ws + OFF_CARR;
  float* qproj = ws + OFF_QPROJ;
  float* yacc  = ws + OFF_YACC;
  float* send  = ws + OFF_SEND;
  float* ptot  = ws + OFF_PTOT;
  float* h0buf = ws + OFF_H0;
  float* hbuf  = ws + OFF_HB;
  u16*   gbuf  = (u16*)(ws + OFF_GBUF);
  float* outqf = ws + OFF_OUTQF;
  float* wprep = ws + OFF_WPREP;
  int*   flag  = (int*)(wprep + 1536);
  u16*   ugbuf = (u16*)(ws + OFF_UG);
  u16*   lnq   = (u16*)(ws + OFF_LNQ);
  u16*   abuf  = (u16*)(ws + OFF_ABUF);
  u16*   aq    = (u16*)(ws + OFF_AQ);
  u16*   bkey  = (u16*)(ws + OFF_BKEY);
  u16*   bq    = (u16*)(ws + OFF_BQ);
  u16*   bok   = (u16*)(ws + OFF_BOK);
  u16*   boq   = (u16*)(ws + OFF_BOQ);
  u16*   b1w   = (u16*)(ws + OFF_B1W);
  u16*   b2w   = (u16*)(ws + OFF_B2W);

  void* out_q = d_out;
  void* out_feat_bf16 = (void*)((u16*)d_out + (size_t)BSZ_*NQ_*DM_);
  void* out_feat_f32  = (void*)((float*)d_out + (size_t)BSZ_*NQ_*DM_);

  // 1. setup: yacc zero + cast0 + detect/prep
  setup_kernel<<<1249, 256, 0, stream>>>(
      features, pos_embed, abuf, queries, query_pos, aq,
      key_proj_w, bkey, query_proj_w, bq,
      A_log, dt_bias, dist_w1, dist_b1, dist_w2, bc_proj_w, dt_proj_w, wprep,
      yacc, flag);

  // 2. kp = abuf @ bkey : (4096 x 1034), K=256
  kp_gemm_kernel<<<dim3(64, 17), 256, 0, stream>>>(abuf, bkey, kp);

  // 3. conv + qproj GEMM
  convqp_kernel<<<4096 + 32, 256, 0, stream>>>(
      flag, kp, key_conv_w, key_conv_b, xact, aq, bq, qproj);

  // 4. dist (standalone, own regalloc)
  dist_kernel<<<BSZ_*LSEQ_/2, 256, 0, stream>>>(flag, anchors, key_pos, kp, xact,
                                                wprep, aw, carr);

  // 5. s1 group-LDS-staged + packed fp32
  s1m_kernel<<<dim3(8, NCHUNK_, BSZ_*NH_), 256, 0, stream>>>(aw, xact, send, ptot);

  // 6. s2
  s2_kernel<<<1024, 256, 0, stream>>>(qproj, ptot, send, h0buf, hbuf);

  // 7. s3 group-LDS-staged + packed fp32 + cast1
  s3cast_kernel<<<2048 + 512, 256, 0, stream>>>(
      flag, aw, carr, xact, h0buf, yacc,
      out_key_proj_w, bok, out_query_proj_w, boq, ffn_fc1_w, b1w, ffn_fc2_w, b2w);

  // 8. g + lnq
  glnq_kernel<<<4096 + 256, 256, 0, stream>>>(
      flag, yacc, xact, kp, Dvec, key_norm_w, gbuf,
      hbuf, query_norm_w, query_norm_b, lnq);

  // 9. out_feat GEMM + outq GEMM
  ofoq_kernel<<<256 + 16, 256, 0, stream>>>(
      flag, gbuf, bok, out_feat_f32, out_feat_bf16, features,
      lnq, boq, outqf, queries);

  // 10. fc1 + gelu with in-block FFN LN
  fc1g_kernel<<<dim3(4, 16), 256, 0, stream>>>(
      flag, outqf, ffn_norm_w, ffn_norm_b, b1w, ffn_fc1_b, ugbuf);

  // 11. fc2: out_q = outqf + ug @ b2w + b2
  fc2_kernel<<<16, 256, 0, stream>>>(flag, ugbuf, b2w, out_q, outqf, ffn_fc2_b);
}

// Round 13
// 373.338 us; speedup vs baseline: 1.1727x; 1.0026x over previous
//
#include <hip/hip_runtime.h>

typedef unsigned short u16;
typedef __bf16 bf16x8 __attribute__((ext_vector_type(8)));
typedef u16 u16x8 __attribute__((ext_vector_type(8)));
typedef u16 u16x2 __attribute__((ext_vector_type(2)));
typedef float f32x4 __attribute__((ext_vector_type(4)));
typedef float f32x2 __attribute__((ext_vector_type(2)));

#define BSZ_ 2
#define NQ_ 128
#define LSEQ_ 2048
#define DM_ 256
#define DI_ 512
#define NH_ 8
#define HD_ 64
#define DKEY_ 1034
#define DCV_ 514
#define NCHUNK_ 16
#define CT_ 128   // chunk length

__device__ __forceinline__ float bf2f(u16 u) {
  unsigned v = ((unsigned)u) << 16;
  return __builtin_bit_cast(float, v);
}
__device__ __forceinline__ u16 f2bf(float f) {
  unsigned u = __builtin_bit_cast(unsigned, f);
  u += 0x7fffu + ((u >> 16) & 1u);
  return (u16)(u >> 16);
}
__device__ __forceinline__ float sigmoidf_(float x) { return 1.f / (1.f + expf(-x)); }
__device__ __forceinline__ float softplusf_(float x) {
  return (x > 20.f) ? x : log1pf(expf(x));
}

template<bool F32>
__device__ __forceinline__ float ldi(const void* p, size_t i) {
  return F32 ? ((const float*)p)[i] : bf2f(((const u16*)p)[i]);
}
template<bool F32>
__device__ __forceinline__ void sto(void* p, size_t i, float v) {
  if (F32) ((float*)p)[i] = v;
  else ((u16*)p)[i] = f2bf(v);
}

// per-wave dtype detection (all waves read same 64 u16s -> uniform result)
__device__ __forceinline__ bool detect_f32(const void* feat) {
  int lane = threadIdx.x & 63;
  float a = fabsf(bf2f(((const u16*)feat)[2*lane]));
  bool plaus = (a > 1e-6f) && (a < 1e6f);
  unsigned long long m = __ballot(plaus);
  return __popcll(m) < 32;   // true => fp32 storage
}

// ---------------- workspace layout (float units) ----------------
constexpr size_t SZ_KP    = (size_t)BSZ_*LSEQ_*DKEY_;
constexpr size_t SZ_XACT  = (size_t)BSZ_*LSEQ_*DCV_;
constexpr size_t SZ_AW    = (size_t)BSZ_*NH_*LSEQ_*NQ_*2;
constexpr size_t SZ_CARR  = (size_t)BSZ_*LSEQ_*NQ_;
constexpr size_t SZ_QPROJ = (size_t)BSZ_*NQ_*DI_;
constexpr size_t SZ_YACC  = (size_t)BSZ_*LSEQ_*DI_;
constexpr size_t SZ_SEND  = (size_t)BSZ_*NH_*2*NCHUNK_*NQ_*HD_;
constexpr size_t SZ_PTOT  = (size_t)BSZ_*NH_*2*NCHUNK_*NQ_;
constexpr size_t SZ_H0    = SZ_SEND;
constexpr size_t SZ_HB    = (size_t)BSZ_*NH_*2*NQ_*HD_;
constexpr size_t SZ_GBUF  = (size_t)BSZ_*LSEQ_*DI_/2;
constexpr size_t SZ_OUTQF = (size_t)BSZ_*NQ_*DM_;
constexpr size_t SZ_WPREP = 2048;

constexpr size_t OFF_KP    = 0;
constexpr size_t OFF_XACT  = OFF_KP + SZ_KP;
constexpr size_t OFF_AW    = OFF_XACT + SZ_XACT;
constexpr size_t OFF_CARR  = OFF_AW + SZ_AW;
constexpr size_t OFF_QPROJ = OFF_CARR + SZ_CARR;
constexpr size_t OFF_YACC  = OFF_QPROJ + SZ_QPROJ;
constexpr size_t OFF_SEND  = OFF_YACC + SZ_YACC;
constexpr size_t OFF_PTOT  = OFF_SEND + SZ_SEND;
constexpr size_t OFF_H0    = OFF_PTOT + SZ_PTOT;
constexpr size_t OFF_HB    = OFF_H0 + SZ_H0;
constexpr size_t OFF_GBUF  = OFF_HB + SZ_HB;
constexpr size_t OFF_OUTQF = OFF_GBUF + SZ_GBUF;
constexpr size_t OFF_WPREP = OFF_OUTQF + SZ_OUTQF;
constexpr size_t WS_FLOATS = OFF_WPREP + SZ_WPREP;

// FFN/outq scratch aliases into AW (dead after s3):
constexpr size_t OFF_UG  = OFF_AW;                         // 256x1024 bf16
constexpr size_t OFF_LNQ = OFF_UG + (size_t)256*1024/2;    // 256x512 bf16

// Transient bf16 cast buffers alias SEND (dead until s1 writes it):
constexpr size_t OFF_ABUF = OFF_SEND;                         // 4096x256 bf16
constexpr size_t OFF_AQ   = OFF_ABUF + (size_t)4096*256/2;
constexpr size_t OFF_BKEY = OFF_AQ + (size_t)256*256/2;
constexpr size_t OFF_BQ   = OFF_BKEY + (size_t)(256*1034+1)/2 + 1;
// Late bf16 weight casts alias SEND (dead after s2):
constexpr size_t OFF_BOK  = OFF_SEND;
constexpr size_t OFF_BOQ  = OFF_BOK + (size_t)512*256/2;
constexpr size_t OFF_B1W  = OFF_BOQ + (size_t)512*256/2;
constexpr size_t OFF_B2W  = OFF_B1W + (size_t)256*2048/2;

// wprep layout: [0..7] A=-exp(A_log); [8..15] dt_bias; [32..287] w1b; [288..1311] w2;
// [1312..1343] bc_proj; [1344..1471] dt_proj
template<bool F32>
__device__ void prep_body(const void* A_log, const void* dt_bias,
                          const void* w1, const void* b1, const void* w2,
                          const void* bcw, const void* dtw, float* wp) {
  int t = threadIdx.x;
  if (t < 8) {
    wp[t]     = -expf(ldi<F32>(A_log, t));
    wp[8 + t] = ldi<F32>(dt_bias, t);
  }
  if (t < 64) {
    wp[32 + t*4 + 0] = ldi<F32>(w1, 0*64 + t);
    wp[32 + t*4 + 1] = ldi<F32>(w1, 1*64 + t);
    wp[32 + t*4 + 2] = ldi<F32>(w1, 2*64 + t);
    wp[32 + t*4 + 3] = ldi<F32>(b1, t);
  }
  for (int i = t; i < 1024; i += 256) wp[288 + i] = ldi<F32>(w2, i);
  if (t < 32)  wp[1312 + t] = ldi<F32>(bcw, t);
  if (t < 128) wp[1344 + t] = ldi<F32>(dtw, t);
}

// cast helper: d[i] = bf16(s0[i] (+ s1_[i]))
__device__ __forceinline__ void cast_job(bool F32, const void* s0, const void* s1_,
                                         u16* d, size_t n, size_t base, size_t stride) {
  for (size_t i = base; i < n; i += stride) {
    float v = F32 ? ((const float*)s0)[i] : bf2f(((const u16*)s0)[i]);
    if (s1_) v += F32 ? ((const float*)s1_)[i] : bf2f(((const u16*)s1_)[i]);
    d[i] = f2bf(v);
  }
}

// ---------------- setup: yacc zero + cast0 + detect/prep (fused) ----------------
__global__ __launch_bounds__(256) void setup_kernel(
    const void* feat, const void* pe, u16* abuf,
    const void* q, const void* qp, u16* aq,
    const void* kw, u16* bkey, const void* qw, u16* bq,
    const void* A_log, const void* dt_bias, const void* w1, const void* b1,
    const void* w2, const void* bcw, const void* dtw, float* wp,
    float* yacc, int* flag)
{
  int bx = blockIdx.x, tid = threadIdx.x;
  if (bx < 512) {                       // yacc zero: 512 blocks x 4096 floats
    size_t base = (size_t)bx * 4096 + tid;
#pragma unroll
    for (int k = 0; k < 16; ++k) yacc[base + (size_t)k*256] = 0.f;
    return;
  }
  bool F32 = detect_f32(feat);
  if (bx < 1024) {                      // abuf = bf16(features + pos_embed)
    cast_job(F32, feat, pe, abuf, (size_t)4096*256,
             (size_t)(bx-512)*256 + tid, (size_t)512*256);
  } else if (bx < 1056) {               // aq = bf16(queries + query_pos)
    cast_job(F32, q, qp, aq, (size_t)256*256,
             (size_t)(bx-1024)*256 + tid, (size_t)32*256);
  } else if (bx < 1184) {               // bkey = bf16(key_proj_w)
    cast_job(F32, kw, nullptr, bkey, (size_t)256*1034,
             (size_t)(bx-1056)*256 + tid, (size_t)128*256);
  } else if (bx < 1248) {               // bq = bf16(query_proj_w)
    cast_job(F32, qw, nullptr, bq, (size_t)256*512,
             (size_t)(bx-1184)*256 + tid, (size_t)64*256);
  } else {                              // detect-store + prep
    if (tid == 0) *flag = F32 ? 1 : 0;
    if (F32) prep_body<true>(A_log, dt_bias, w1, b1, w2, bcw, dtw, wp);
    else     prep_body<false>(A_log, dt_bias, w1, b1, w2, bcw, dtw, wp);
  }
}

// ---------------- MFMA GEMM body (Bs padded to 42: bank-conflict-free) ----------
// BV: B-stage vector width. 2 = unconditional u16x8 (row stride 16B-aligned,
// tiles always full: N in {256,512,1024,2048}); 1 = guarded 4x u16x2
// (4B-aligned only, N=1034); 0 = scalar fallback.
template<int A_MODE, int B_MODE, int BV, int OUT_EEXT, int RES_EXT, int RES_F32, int BIAS, bool F32>
__device__ void gemm_body(int bm, int bn,
                          const void* A0, const void* A1, const void* Bw,
                          float* Cf, void* Cext, const void* ResE,
                          const float* ResF, const void* Bias,
                          int M, int N, int K) {
  __shared__ u16 As[64][40];
  __shared__ u16 Bs[64][42];
  int tid = threadIdx.x;
  int w = tid >> 6, lane = tid & 63;
  f32x4 acc[4];
#pragma unroll
  for (int j = 0; j < 4; ++j) acc[j] = (f32x4){0.f, 0.f, 0.f, 0.f};

  int arow = tid >> 2, aseg = (tid & 3) * 8;
  int bkl = tid >> 3, bns = (tid & 7) * 8;

  for (int k0 = 0; k0 < K; k0 += 32) {
    {
      size_t abase = (size_t)(bm + arow) * K + k0 + aseg;
      u16x8 tv;
      if (A_MODE == 0) {
#pragma unroll
        for (int i = 0; i < 8; ++i)
          tv[i] = f2bf(ldi<F32>(A0, abase + i) + ldi<F32>(A1, abase + i));
      } else {
        tv = *(const u16x8*)((const u16*)A0 + abase);   // 16B-aligned for all uses
      }
      *(u16x8*)&As[arow][aseg] = tv;
    }
    {
      size_t bbase = (size_t)(k0 + bkl) * N + bn + bns;
      if (BV == 2) {
        u16x8 bv8 = *(const u16x8*)((const u16*)Bw + bbase);
#pragma unroll
        for (int i = 0; i < 8; ++i) Bs[bns + i][bkl] = bv8[i];
      } else if (BV == 1 && bn + bns + 8 <= N) {
        const u16* bp = (const u16*)Bw + bbase;
#pragma unroll
        for (int i2 = 0; i2 < 4; ++i2) {
          u16x2 v2 = *(const u16x2*)(bp + i2*2);
          Bs[bns + i2*2][bkl]     = v2[0];
          Bs[bns + i2*2 + 1][bkl] = v2[1];
        }
      } else {
#pragma unroll
        for (int i = 0; i < 8; ++i) {
          u16 v;
          if (bn + bns + i < N) {
            if (B_MODE == 1) v = ((const u16*)Bw)[bbase + i];
            else             v = f2bf(ldi<F32>(Bw, bbase + i));
          } else v = (u16)0;
          Bs[bns + i][bkl] = v;
        }
      }
    }
    __syncthreads();
    int mrow = w * 16 + (lane & 15);
    int kq = (lane >> 4) * 8;
    bf16x8 af = __builtin_bit_cast(bf16x8, *(const u16x8*)&As[mrow][kq]);
#pragma unroll
    for (int j = 0; j < 4; ++j) {
      bf16x8 bfv = __builtin_bit_cast(bf16x8, *(const u16x8*)&Bs[j*16 + (lane & 15)][kq]);
      acc[j] = __builtin_amdgcn_mfma_f32_16x16x32_bf16(af, bfv, acc[j], 0, 0, 0);
    }
    __syncthreads();
  }
  int col0 = lane & 15, rbase = (lane >> 4) * 4;
#pragma unroll
  for (int j = 0; j < 4; ++j) {
#pragma unroll
    for (int r = 0; r < 4; ++r) {
      int row = bm + w * 16 + rbase + r;
      int col = bn + j * 16 + col0;
      if (col < N) {
        size_t idx = (size_t)row * N + col;
        float v = acc[j][r];
        if (BIAS)     v += ldi<F32>(Bias, col);
        if (RES_EXT)  v += ldi<F32>(ResE, idx);
        if (RES_F32)  v += ResF[idx];
        if (OUT_EEXT) sto<F32>(Cext, idx, v);
        else          Cf[idx] = v;
      }
    }
  }
}

// kp = abuf @ bkey (all-internal bf16, fp32 out); N=1034 -> BV=1 (4B-aligned)
__global__ __launch_bounds__(256) void kp_gemm_kernel(
    const u16* abuf, const u16* bkey, float* kp) {
  gemm_body<1,1,1,0,0,0,0,false>(blockIdx.x*64, blockIdx.y*64, abuf, nullptr, bkey,
                                 kp, nullptr, nullptr, nullptr, nullptr,
                                 4096, DKEY_, DM_);
}

// fc2: out_q = outqf + ug @ b2w + b2
template<bool F32>
__device__ void fc2_body(const u16* ug, const u16* b2w, void* out_q,
                         const float* outqf, const void* b2) {
  gemm_body<1,1,2,1,0,1,1,F32>((blockIdx.x&3)*64, (blockIdx.x>>2)*64, ug, nullptr,
                               b2w, nullptr, out_q, nullptr, outqf, b2,
                               BSZ_*NQ_, DM_, 1024);
}
__global__ __launch_bounds__(256) void fc2_kernel(
    const int* fl, const u16* ug, const u16* b2w, void* out_q,
    const float* outqf, const void* b2) {
  if (*fl) fc2_body<true>(ug, b2w, out_q, outqf, b2);
  else     fc2_body<false>(ug, b2w, out_q, outqf, b2);
}

// ---------------- conv + qproj GEMM (fused, independent blocks) ----------------
template<bool F32>
__device__ void conv_body(const float* kp, const void* cw, const void* cb,
                          float* xact) {
  int row = blockIdx.x;
  int l = row & (LSEQ_ - 1);
  for (int ch = threadIdx.x; ch < DCV_; ch += 256) {
    float acc = ldi<F32>(cb, ch);
#pragma unroll
    for (int k = 0; k < 4; ++k) {
      int ll = l - 3 + k;
      if (ll >= 0)
        acc = fmaf(ldi<F32>(cw, ch*4 + k), kp[(size_t)(row - 3 + k)*DKEY_ + DI_ + ch], acc);
    }
    xact[(size_t)row*DCV_ + ch] = acc * sigmoidf_(acc);
  }
}
__global__ __launch_bounds__(256) void convqp_kernel(
    const int* fl, const float* kp, const void* cw, const void* cb, float* xact,
    const u16* aq, const u16* bq, float* qproj)
{
  int bx = blockIdx.x;
  if (bx < 4096) {
    if (*fl) conv_body<true>(kp, cw, cb, xact);
    else     conv_body<false>(kp, cw, cb, xact);
  } else {
    int i = bx - 4096;   // 32 blocks: M=256 (4 tiles) x N=512 (8 tiles)
    gemm_body<1,1,2,0,0,0,0,false>((i&3)*64, (i>>2)*64, aq, nullptr, bq,
                                   qproj, nullptr, nullptr, nullptr, nullptr,
                                   BSZ_*NQ_, DI_, DM_);
  }
}

// ---------------- dist MLP -> a, w, c (standalone, own regalloc) ---------------
template<bool F32>
__device__ void dist_body(const void* anchors, const void* key_pos,
                          const float* kp, const float* xact, const float* wp,
                          float* aw, float* carr) {
  int tid = threadIdx.x;
  int n = tid & 127;
  int idx = blockIdx.x;
  int b = idx >> 10;
  int l = ((idx & 1023) << 1) | (tid >> 7);
  size_t row = (size_t)b * LSEQ_ + l;

  float enc0, enc1, enc2;
  {
    float e[3];
#pragma unroll
    for (int d = 0; d < 3; ++d) {
      float delta = ldi<F32>(anchors, (b*NQ_ + n)*3 + d) - ldi<F32>(key_pos, row*3 + d);
      float s = delta < 0.f ? -1.f : 1.f;
      e[d] = s * log2f(fabsf(delta) * 20.f + 1.f) * (1.f/12.f);
    }
    enc0 = e[0]; enc1 = e[1]; enc2 = e[2];
  }
  float feat[16];
#pragma unroll
  for (int f = 0; f < 16; ++f) feat[f] = 0.f;
  for (int j = 0; j < 64; ++j) {
    float w0 = wp[32 + j*4], w1v = wp[33 + j*4], w2v = wp[34 + j*4], bb = wp[35 + j*4];
    float hj = fmaxf(fmaf(enc0, w0, fmaf(enc1, w1v, fmaf(enc2, w2v, bb))), 0.f);
#pragma unroll
    for (int f = 0; f < 16; ++f) feat[f] = fmaf(hj, wp[288 + j*16 + f], feat[f]);
  }
  float bc0 = 0.f, bc1 = 0.f;
#pragma unroll
  for (int f = 0; f < 16; ++f) {
    bc0 = fmaf(feat[f], wp[1312 + f*2], bc0);
    bc1 = fmaf(feat[f], wp[1313 + f*2], bc1);
  }
  float bb_ = xact[row*DCV_ + DI_];
  float cb_ = xact[row*DCV_ + DI_ + 1];
  float Bs = bc0 + bb_, Cs = bc1 + cb_;
  carr[row*NQ_ + n] = Cs;

  float dtb[8];
#pragma unroll
  for (int h = 0; h < 8; ++h) dtb[h] = 0.f;
#pragma unroll
  for (int f = 0; f < 16; ++f)
#pragma unroll
    for (int h = 0; h < 8; ++h) dtb[h] = fmaf(feat[f], wp[1344 + f*8 + h], dtb[h]);

#pragma unroll
  for (int h = 0; h < 8; ++h) {
    float xln = dtb[h] + kp[row*DKEY_ + (DI_*2 + 2) + h] + wp[8 + h];
    float dtv = softplusf_(xln);
    float a = expf(dtv * wp[h]);
    float wv = dtv * Bs;
    size_t o = (((size_t)(b*NH_ + h)*LSEQ_ + l)*NQ_ + n)*2;
    aw[o] = a;
    aw[o + 1] = wv;
  }
}
__global__ __launch_bounds__(256) void dist_kernel(
    const int* fl, const void* anchors, const void* key_pos, const float* kp,
    const float* xact, const float* wp, float* aw, float* carr) {
  if (*fl) dist_body<true>(anchors, key_pos, kp, xact, wp, aw, carr);
  else     dist_body<false>(anchors, key_pos, kp, xact, wp, aw, carr);
}

// ---------------- scan phase 1: group-LDS-staged + packed fp32 + b128 reads ----
__global__ __launch_bounds__(256) void s1m_kernel(
    const float* __restrict__ aw, const float* __restrict__ xact,
    float* __restrict__ send, float* __restrict__ ptot)
{
  __shared__ float awa[2][8][16];   // 1 KB
  __shared__ float aww[2][8][16];   // 1 KB
  __shared__ float xl [2][8][64];   // 4 KB
  int tid = threadIdx.x;
  int hd = tid & 63;
  int w = __builtin_amdgcn_readfirstlane(tid >> 6);
  int ns = blockIdx.x, q = blockIdx.y, z = blockIdx.z;   // z = b*NH_ + h
  int h = z & 7, b = z >> 3;
  int n0 = __builtin_amdgcn_readfirstlane(ns*16 + w*4);

  f32x2 hf01 = {0.f,0.f}, hf23 = {0.f,0.f};
  f32x2 hb01 = {0.f,0.f}, hb23 = {0.f,0.f};
  f32x2 pr01 = {1.f,1.f}, pr23 = {1.f,1.f};

  // stage thread mapping: s8 = step-in-group (0..7), j = 0..31
  int s8 = tid >> 5, j = tid & 31;
  int t0 = q*CT_;
  const float* awg = aw + (size_t)z*LSEQ_*(NQ_*2)
                     + (size_t)(t0 + s8)*(NQ_*2) + ns*32 + (j & 15)*2;
  const float* xg  = xact + ((size_t)(b*LSEQ_) + t0 + s8)*DCV_ + (h<<6) + j*2;
  const long awgstep = 8L*(NQ_*2);
  const long xgstep  = 8L*DCV_;

  // prologue: stage group 0 (threads j<16 stage the 16 (a,w) pairs per step)
  {
    f32x2 pa = *(const f32x2*)awg;
    f32x2 px = *(const f32x2*)xg;
    awg += awgstep; xg += xgstep;
    if (j < 16) { awa[0][s8][j] = pa[0]; aww[0][s8][j] = pa[1]; }
    *(f32x2*)&xl[0][s8][j*2] = px;
  }
  asm volatile("s_waitcnt lgkmcnt(0)" ::: "memory");
  __builtin_amdgcn_s_barrier();

  int p = 0;
  f32x2 sa; f32x2 sx;
  for (int g = 0; g < 16; ++g) {
    if (g < 15) {
      sa = *(const f32x2*)awg; sx = *(const f32x2*)xg;
      awg += awgstep; xg += xgstep;
    }
#pragma unroll
    for (int s = 0; s < 8; ++s) {
      f32x4 av = *(const f32x4*)&awa[p][s][w*4];   // ds_read_b128 (16B-aligned)
      f32x4 wv = *(const f32x4*)&aww[p][s][w*4];   // ds_read_b128
      float xv = xl[p][s][hd];
      f32x2 a01 = {av[0], av[1]}, a23 = {av[2], av[3]};
      f32x2 w01 = {wv[0], wv[1]}, w23 = {wv[2], wv[3]};
      f32x2 xv2 = {xv, xv};
      f32x2 wx0 = w01 * xv2;
      f32x2 wx1 = w23 * xv2;
      hf01 = hf01 * a01 + wx0;
      hf23 = hf23 * a23 + wx1;
      hb01 = pr01 * wx0 + hb01;
      hb23 = pr23 * wx1 + hb23;
      pr01 = pr01 * a01;
      pr23 = pr23 * a23;
    }
    if (g < 15) {
      if (j < 16) { awa[p^1][s8][j] = sa[0]; aww[p^1][s8][j] = sa[1]; }
      *(f32x2*)&xl[p^1][s8][j*2] = sx;
    }
    asm volatile("s_waitcnt lgkmcnt(0)" ::: "memory");
    __builtin_amdgcn_s_barrier();
    p ^= 1;
  }

  float hf[4] = {hf01[0], hf01[1], hf23[0], hf23[1]};
  float hb[4] = {hb01[0], hb01[1], hb23[0], hb23[1]};
  float pr[4] = {pr01[0], pr01[1], pr23[0], pr23[1]};
  size_t cbf = (size_t)((z*2 + 0)*NCHUNK_ + q);
  size_t cbb = (size_t)((z*2 + 1)*NCHUNK_ + (NCHUNK_ - 1 - q));
#pragma unroll
  for (int i = 0; i < 4; ++i) {
    send[cbf*(NQ_*HD_) + (size_t)(n0 + i)*HD_ + hd] = hf[i];
    send[cbb*(NQ_*HD_) + (size_t)(n0 + i)*HD_ + hd] = hb[i];
  }
  if (hd == 0) {
#pragma unroll
    for (int i = 0; i < 4; ++i) {
      ptot[cbf*NQ_ + n0 + i] = pr[i];
      ptot[cbb*NQ_ + n0 + i] = pr[i];
    }
  }
}

// ---------------- scan phase 2 ----------------
__global__ __launch_bounds__(256) void s2_kernel(
    const float* __restrict__ qproj, const float* __restrict__ ptot,
    const float* __restrict__ send, float* __restrict__ h0buf,
    float* __restrict__ hbuf)
{
  int g = blockIdx.x*256 + threadIdx.x;
  int hd = g & 63;
  int n = (g >> 6) & 127;
  int dir = (g >> 13) & 1;
  int h = (g >> 14) & 7;
  int b = g >> 17;
  float hcur = qproj[((size_t)(b*NQ_ + n))*DI_ + h*HD_ + hd];
  size_t base = (size_t)((b*NH_ + h)*2 + dir) * NCHUNK_;
  for (int q = 0; q < NCHUNK_; ++q) {
    size_t cb = base + q;
    h0buf[cb*(NQ_*HD_) + (size_t)n*HD_ + hd] = hcur;
    hcur = fmaf(hcur, ptot[cb*NQ_ + n], send[cb*(NQ_*HD_) + (size_t)n*HD_ + hd]);
  }
  hbuf[((size_t)((b*NH_ + h)*2 + dir))*(NQ_*HD_) + (size_t)n*HD_ + hd] = hcur;
}

// ---------------- scan phase 3: staged + packed fp32 + b128 LDS reads + cast1 --
// r11 shifted the binder from VALU (67->38% busy) to LDS issue: the f32x2
// operand reads were ~12 narrow ds_reads/step. Explicit f32x4 reads cut the
// operand reads to 6x ds_read_b128 (LDS instr overhead ~5-6cy regardless of
// width -> fewer, wider wins). Packed math consumes register-aliased halves;
// summation order bit-identical to r11.
template<bool F32>
__device__ void cast1_part(const void* okw, u16* bok, const void* oqw, u16* boq,
                           const void* w1, u16* b1w, const void* w2, u16* b2w) {
  int i = blockIdx.x - 2048;
  int job = i >> 7, bj = i & 127;
  size_t base = (size_t)bj*256 + threadIdx.x, stride = (size_t)128*256;
  switch (job) {
    case 0: cast_job(F32, okw, nullptr, bok, (size_t)512*256, base, stride); break;
    case 1: cast_job(F32, oqw, nullptr, boq, (size_t)512*256, base, stride); break;
    case 2: cast_job(F32, w1, nullptr, b1w, (size_t)256*2048, base, stride); break;
    default: cast_job(F32, w2, nullptr, b2w, (size_t)1024*256, base, stride); break;
  }
}
__global__ __launch_bounds__(256) void s3cast_kernel(
    const int* fl, const float* __restrict__ aw, const float* __restrict__ carr,
    const float* __restrict__ xact, const float* __restrict__ h0buf,
    float* __restrict__ yacc,
    const void* okw, u16* bok, const void* oqw, u16* boq,
    const void* w1, u16* b1w, const void* w2, u16* b2w)
{
  int bx = blockIdx.x;
  if (bx >= 2048) {
    if (*fl) cast1_part<true>(okw, bok, oqw, boq, w1, b1w, w2, b2w);
    else     cast1_part<false>(okw, bok, oqw, boq, w1, b1w, w2, b2w);
    return;
  }
  __shared__ float awa[2][8][32];   // 2 KB
  __shared__ float aww[2][8][32];   // 2 KB
  __shared__ float ctl[2][8][32];   // 2 KB
  __shared__ float xl [2][8][64];   // 4 KB
  __shared__ float yl [8][4][64];   // 8 KB  -> total 18 KB

  int tid = threadIdx.x;
  int hd = tid & 63;
  int w = __builtin_amdgcn_readfirstlane(tid >> 6);
  int ns = bx & 3, q = (bx >> 2) & 15, zz = bx >> 6;
  int dir = zz & 1, h = (zz >> 1) & 7, b = zz >> 4;
  int z = b*NH_ + h;
  int n0 = ns*32 + w*8;

  int tbase = dir ? (LSEQ_ - 1 - q*CT_) : (q*CT_);
  int tstep = dir ? -1 : 1;

  // stage thread mapping: s8 = step-in-group, j = 0..31 (pair for n=ns*32+j)
  int s8 = tid >> 5, j = tid & 31;
  const float* awg = aw + (size_t)z*LSEQ_*(NQ_*2)
                     + (size_t)(tbase + tstep*s8)*(NQ_*2) + ns*64 + j*2;
  const float* ctg = carr + ((size_t)(b*LSEQ_) + tbase + tstep*s8)*NQ_ + ns*32 + j;
  const float* xg  = xact + ((size_t)(b*LSEQ_) + tbase + tstep*s8)*DCV_ + (h<<6) + j*2;
  long awgstep = (long)tstep*8*(NQ_*2);
  long ctgstep = (long)tstep*8*NQ_;
  long xgstep  = (long)tstep*8*DCV_;

  // prologue: issue stage(group 0) loads first (deep), then h0 state loads
  f32x2 pa = *(const f32x2*)awg;
  float pc = *ctg;
  f32x2 px = *(const f32x2*)xg;
  awg += awgstep; ctg += ctgstep; xg += xgstep;

  f32x2 h01, h23, h45, h67;
  {
    size_t cb = (size_t)((z*2 + dir)*NCHUNK_ + q);
    const float* hp = h0buf + cb*(NQ_*HD_) + (size_t)n0*HD_ + hd;
    h01 = (f32x2){hp[0*HD_], hp[1*HD_]};
    h23 = (f32x2){hp[2*HD_], hp[3*HD_]};
    h45 = (f32x2){hp[4*HD_], hp[5*HD_]};
    h67 = (f32x2){hp[6*HD_], hp[7*HD_]};
  }
  awa[0][s8][j] = pa[0];
  aww[0][s8][j] = pa[1];
  ctl[0][s8][j] = pc;
  *(f32x2*)&xl[0][s8][j*2] = px;
  asm volatile("s_waitcnt lgkmcnt(0)" ::: "memory");
  __builtin_amdgcn_s_barrier();

  float* yrow = yacc + ((size_t)(b*LSEQ_) + tbase)*DI_ + (h << 6) + hd;
  long ystep = (long)tstep * DI_;

  int p = 0;
  f32x2 sa; float sc; f32x2 sx;
  for (int g = 0; g < 16; ++g) {
    if (g < 15) {
      sa = *(const f32x2*)awg; sc = *ctg; sx = *(const f32x2*)xg;
      awg += awgstep; ctg += ctgstep; xg += xgstep;
    }
    if (g > 0) {
#pragma unroll
      for (int r = 0; r < 2; ++r) {
        int s = w + r*4;
        float yv = yl[s][0][hd] + yl[s][1][hd] + yl[s][2][hd] + yl[s][3][hd];
        atomicAdd(yrow + (long)((g-1)*8 + s)*ystep, 0.5f * yv);
      }
    }
    asm volatile("s_waitcnt lgkmcnt(0)" ::: "memory");
    __builtin_amdgcn_s_barrier();           // yl reads done before overwrite
#pragma unroll
    for (int s = 0; s < 8; ++s) {
      f32x4 A0 = *(const f32x4*)&awa[p][s][w*8];       // ds_read_b128
      f32x4 A1 = *(const f32x4*)&awa[p][s][w*8 + 4];
      f32x4 W0 = *(const f32x4*)&aww[p][s][w*8];
      f32x4 W1 = *(const f32x4*)&aww[p][s][w*8 + 4];
      f32x4 C0 = *(const f32x4*)&ctl[p][s][w*8];
      f32x4 C1 = *(const f32x4*)&ctl[p][s][w*8 + 4];
      float xv = xl[p][s][hd];
      f32x2 a01 = {A0[0], A0[1]}, a23 = {A0[2], A0[3]};
      f32x2 a45 = {A1[0], A1[1]}, a67 = {A1[2], A1[3]};
      f32x2 w01 = {W0[0], W0[1]}, w23 = {W0[2], W0[3]};
      f32x2 w45 = {W1[0], W1[1]}, w67 = {W1[2], W1[3]};
      f32x2 c01 = {C0[0], C0[1]}, c23 = {C0[2], C0[3]};
      f32x2 c45 = {C1[0], C1[1]}, c67 = {C1[2], C1[3]};
      f32x2 xv2 = {xv, xv};
      f32x2 wx, ys2;
      wx = w01 * xv2; h01 = h01 * a01 + wx; ys2 = h01 * c01;
      wx = w23 * xv2; h23 = h23 * a23 + wx; ys2 += h23 * c23;
      wx = w45 * xv2; h45 = h45 * a45 + wx; ys2 += h45 * c45;
      wx = w67 * xv2; h67 = h67 * a67 + wx; ys2 += h67 * c67;
      yl[s][w][hd] = ys2[0] + ys2[1];
    }
    if (g < 15) {
      awa[p^1][s8][j] = sa[0];
      aww[p^1][s8][j] = sa[1];
      ctl[p^1][s8][j] = sc;
      *(f32x2*)&xl[p^1][s8][j*2] = sx;
    }
    asm volatile("s_waitcnt lgkmcnt(0)" ::: "memory");
    __builtin_amdgcn_s_barrier();           // staged buffer ready for g+1
    p ^= 1;
  }
#pragma unroll
  for (int r = 0; r < 2; ++r) {
    int s = w + r*4;
    float yv = yl[s][0][hd] + yl[s][1][hd] + yl[s][2][hd] + yl[s][3][hd];
    atomicAdd(yrow + (long)(15*8 + s)*ystep, 0.5f * yv);
  }
}

// ---------------- block reduction helper ----------------
__device__ __forceinline__ float block_sum256(float v, float* red) {
#pragma unroll
  for (int off = 32; off; off >>= 1) v += __shfl_xor(v, off, 64);
  int wv = threadIdx.x >> 6;
  if ((threadIdx.x & 63) == 0) red[wv] = v;
  __syncthreads();
  float t = red[0] + red[1] + red[2] + red[3];
  __syncthreads();
  return t;
}

// ---------------- g (gated RMSNorm) + lnq (fused) ----------------
template<bool F32>
__device__ void g_body(const float* yacc, const float* xact, const float* kp,
                       const void* Dv, const void* knw, u16* gbuf) {
  int row = blockIdx.x, tid = threadIdx.x;
  __shared__ float red[4];
  float gg[2];
  float ss = 0.f;
#pragma unroll
  for (int ii = 0; ii < 2; ++ii) {
    int ch = tid + ii*256;
    float yv = yacc[(size_t)row*DI_ + ch];
    float xv = xact[(size_t)row*DCV_ + ch];
    float zv = kp[(size_t)row*DKEY_ + ch];
    float Dh = ldi<F32>(Dv, ch >> 6);
    float yf = yv + 2.f * Dh * xv;
    float g = yf * (zv * sigmoidf_(zv));
    gg[ii] = g;
    ss += g * g;
  }
  float tot = block_sum256(ss, red);
  float r = rsqrtf(tot / (float)DI_ + 1e-5f);
#pragma unroll
  for (int ii = 0; ii < 2; ++ii) {
    int ch = tid + ii*256;
    gbuf[(size_t)row*DI_ + ch] = f2bf(gg[ii] * r * ldi<F32>(knw, ch));
  }
}
template<bool F32>
__device__ void lnq_body(const float* hbuf, const void* qnw, const void* qnb,
                         u16* lnq) {
  int row = blockIdx.x - 4096;
  int b = row >> 7, n = row & 127;
  int tid = threadIdx.x;
  __shared__ float red[4];
  float hv[2];
  float s1 = 0.f, s2 = 0.f;
#pragma unroll
  for (int ii = 0; ii < 2; ++ii) {
    int ch = tid + ii*256;
    int h = ch >> 6, hd = ch & 63;
    size_t base = ((size_t)((b*NH_ + h)*2))*(NQ_*HD_) + (size_t)n*HD_ + hd;
    float v = 0.5f * (hbuf[base] + hbuf[base + (size_t)NQ_*HD_]);
    hv[ii] = v;
    s1 += v;
    s2 += v * v;
  }
  s1 = block_sum256(s1, red);
  s2 = block_sum256(s2, red);
  float mean = s1 / (float)DI_;
  float var = fmaxf(s2 / (float)DI_ - mean * mean, 0.f);
  float rstd = rsqrtf(var + 1e-5f);
#pragma unroll
  for (int ii = 0; ii < 2; ++ii) {
    int ch = tid + ii*256;
    lnq[(size_t)row*DI_ + ch] =
        f2bf((hv[ii] - mean) * rstd * ldi<F32>(qnw, ch) + ldi<F32>(qnb, ch));
  }
}
__global__ __launch_bounds__(256) void glnq_kernel(
    const int* fl, const float* yacc, const float* xact, const float* kp,
    const void* Dv, const void* knw, u16* gbuf,
    const float* hbuf, const void* qnw, const void* qnb, u16* lnq)
{
  if (blockIdx.x < 4096) {
    if (*fl) g_body<true>(yacc, xact, kp, Dv, knw, gbuf);
    else     g_body<false>(yacc, xact, kp, Dv, knw, gbuf);
  } else {
    if (*fl) lnq_body<true>(hbuf, qnw, qnb, lnq);
    else     lnq_body<false>(hbuf, qnw, qnb, lnq);
  }
}

// ---------------- out_feat GEMM + outq GEMM (fused) ----------------
template<bool F32>
__device__ void ofoq_body(const u16* gbuf, const u16* bok, void* out_feat,
                          const void* features, const u16* lnq, const u16* boq,
                          float* outqf, const void* queries) {
  int bx = blockIdx.x;
  if (bx < 256) {   // out_feat: M=4096 (64 tiles) x N=256 (4 tiles), K=512
    gemm_body<1,1,2,1,1,0,0,F32>((bx>>2)*64, (bx&3)*64, gbuf, nullptr, bok,
                                 nullptr, out_feat, features, nullptr, nullptr,
                                 4096, DM_, DI_);
  } else {          // outq: M=256 (4) x N=256 (4), K=512
    int i = bx - 256;
    gemm_body<1,1,2,0,1,0,0,F32>((i&3)*64, (i>>2)*64, lnq, nullptr, boq,
                                 outqf, nullptr, queries, nullptr, nullptr,
                                 BSZ_*NQ_, DM_, DI_);
  }
}
__global__ __launch_bounds__(256) void ofoq_kernel(
    const int* fl, const u16* gbuf, const u16* bok,
    void* out_feat_f32, void* out_feat_bf16, const void* features,
    const u16* lnq, const u16* boq, float* outqf, const void* queries) {
  if (*fl) ofoq_body<true>(gbuf, bok, out_feat_f32, features, lnq, boq, outqf, queries);
  else     ofoq_body<false>(gbuf, bok, out_feat_bf16, features, lnq, boq, outqf, queries);
}

// ---------------- fc1 + gelu, with IN-BLOCK FFN LayerNorm (lnf kernel removed) --
template<bool F32>
__device__ void fc1g_body(const float* outqf, const void* fnw, const void* fnb,
                          const u16* b1w, const void* b1, u16* ug) {
  __shared__ u16 Asf[64][264];   // 33 KB
  __shared__ u16 BsA[64][42];
  __shared__ u16 BsV[64][42];
  __shared__ float red1[64][4];
  __shared__ float red2[64][4];
  int tid = threadIdx.x;
  int w = tid >> 6, lane = tid & 63;
  int bm = blockIdx.x * 64, bn = blockIdx.y * 64;   // bn in [0,1024)

  // ---- in-block LN of outqf rows [bm, bm+64) ----
  {
    int r = tid >> 2, qt = tid & 3;
    const float* src = outqf + (size_t)(bm + r)*DM_ + qt*64;
    float v[64];
    float s1 = 0.f, s2 = 0.f;
#pragma unroll
    for (int i = 0; i < 64; ++i) { v[i] = src[i]; s1 += v[i]; s2 += v[i]*v[i]; }
    red1[r][qt] = s1; red2[r][qt] = s2;
    __syncthreads();
    float t1 = red1[r][0] + red1[r][1] + red1[r][2] + red1[r][3];
    float t2 = red2[r][0] + red2[r][1] + red2[r][2] + red2[r][3];
    float mean = t1 / (float)DM_;
    float var = fmaxf(t2 / (float)DM_ - mean * mean, 0.f);
    float rstd = rsqrtf(var + 1e-5f);
#pragma unroll
    for (int i = 0; i < 64; ++i) {
      int col = qt*64 + i;
      Asf[r][col] = f2bf((v[i] - mean) * rstd * ldi<F32>(fnw, col)
                         + ldi<F32>(fnb, col));
    }
    __syncthreads();
  }

  f32x4 accA[4], accV[4];
#pragma unroll
  for (int j = 0; j < 4; ++j) {
    accA[j] = (f32x4){0.f, 0.f, 0.f, 0.f};
    accV[j] = (f32x4){0.f, 0.f, 0.f, 0.f};
  }
  int bkl = tid >> 3, bns = (tid & 7) * 8;

  for (int k0 = 0; k0 < DM_; k0 += 32) {
    {
      size_t bbase = (size_t)(k0 + bkl) * 2048 + bn + bns;
      u16x8 ba8 = *(const u16x8*)(b1w + bbase);          // 16B-aligned
      u16x8 bv8 = *(const u16x8*)(b1w + bbase + 1024);
#pragma unroll
      for (int i = 0; i < 8; ++i) {
        BsA[bns + i][bkl] = ba8[i];
        BsV[bns + i][bkl] = bv8[i];
      }
    }
    __syncthreads();
    int mrow = w * 16 + (lane & 15);
    int kq = (lane >> 4) * 8;
    bf16x8 af = __builtin_bit_cast(bf16x8, *(const u16x8*)&Asf[mrow][k0 + kq]);
#pragma unroll
    for (int j = 0; j < 4; ++j) {
      bf16x8 ba = __builtin_bit_cast(bf16x8, *(const u16x8*)&BsA[j*16 + (lane & 15)][kq]);
      bf16x8 bv = __builtin_bit_cast(bf16x8, *(const u16x8*)&BsV[j*16 + (lane & 15)][kq]);
      accA[j] = __builtin_amdgcn_mfma_f32_16x16x32_bf16(af, ba, accA[j], 0, 0, 0);
      accV[j] = __builtin_amdgcn_mfma_f32_16x16x32_bf16(af, bv, accV[j], 0, 0, 0);
    }
    __syncthreads();
  }
  int col0 = lane & 15, rbase = (lane >> 4) * 4;
#pragma unroll
  for (int j = 0; j < 4; ++j) {
#pragma unroll
    for (int r = 0; r < 4; ++r) {
      int row = bm + w * 16 + rbase + r;
      int col = bn + j * 16 + col0;
      float a = accA[j][r] + ldi<F32>(b1, col);
      float v = accV[j][r] + ldi<F32>(b1, col + 1024);
      float ge = 0.5f * a * (1.f + erff(a * 0.70710678118f));
      ug[(size_t)row*1024 + col] = f2bf(ge * v);
    }
  }
}
__global__ __launch_bounds__(256) void fc1g_kernel(
    const int* fl, const float* outqf, const void* fnw, const void* fnb,
    const u16* b1w, const void* b1, u16* ug) {
  if (*fl) fc1g_body<true>(outqf, fnw, fnb, b1w, b1, ug);
  else     fc1g_body<false>(outqf, fnw, fnb, b1w, b1, ug);
}

// ---------------- launch ----------------
extern "C" void kernel_launch(void* const* d_in, const int* in_sizes, int n_in,
                              void* d_out, int out_size, void* d_ws, size_t ws_size,
                              hipStream_t stream) {
  const void* queries        = d_in[0];
  const void* anchors        = d_in[1];
  const void* features       = d_in[2];
  const void* pos_embed      = d_in[3];
  const void* key_pos        = d_in[4];
  const void* query_pos      = d_in[5];
  const void* key_proj_w     = d_in[6];
  const void* key_conv_w     = d_in[7];
  const void* key_conv_b     = d_in[8];
  const void* query_proj_w   = d_in[9];
  const void* dist_w1        = d_in[10];
  const void* dist_b1        = d_in[11];
  const void* dist_w2        = d_in[12];
  const void* bc_proj_w      = d_in[13];
  const void* dt_proj_w      = d_in[14];
  const void* dt_bias        = d_in[15];
  const void* A_log          = d_in[16];
  const void* Dvec           = d_in[17];
  const void* key_norm_w     = d_in[18];
  const void* out_key_proj_w = d_in[19];
  const void* query_norm_w   = d_in[20];
  const void* query_norm_b   = d_in[21];
  const void* out_query_proj_w = d_in[22];
  const void* ffn_norm_w     = d_in[23];
  const void* ffn_norm_b     = d_in[24];
  const void* ffn_fc1_w      = d_in[25];
  const void* ffn_fc1_b      = d_in[26];
  const void* ffn_fc2_w      = d_in[27];
  const void* ffn_fc2_b      = d_in[28];

  if (ws_size < WS_FLOATS * sizeof(float)) return;

  float* ws    = (float*)d_ws;
  float* kp    = ws + OFF_KP;
  float* xact  = ws + OFF_XACT;
  float* aw    = ws + OFF_AW;
  float* carr  = ws + OFF_CARR;
  float* qproj = ws + OFF_QPROJ;
  float* yacc  = ws + OFF_YACC;
  float* send  = ws + OFF_SEND;
  float* ptot  = ws + OFF_PTOT;
  float* h0buf = ws + OFF_H0;
  float* hbuf  = ws + OFF_HB;
  u16*   gbuf  = (u16*)(ws + OFF_GBUF);
  float* outqf = ws + OFF_OUTQF;
  float* wprep = ws + OFF_WPREP;
  int*   flag  = (int*)(wprep + 1536);
  u16*   ugbuf = (u16*)(ws + OFF_UG);
  u16*   lnq   = (u16*)(ws + OFF_LNQ);
  u16*   abuf  = (u16*)(ws + OFF_ABUF);
  u16*   aq    = (u16*)(ws + OFF_AQ);
  u16*   bkey  = (u16*)(ws + OFF_BKEY);
  u16*   bq    = (u16*)(ws + OFF_BQ);
  u16*   bok   = (u16*)(ws + OFF_BOK);
  u16*   boq   = (u16*)(ws + OFF_BOQ);
  u16*   b1w   = (u16*)(ws + OFF_B1W);
  u16*   b2w   = (u16*)(ws + OFF_B2W);

  void* out_q = d_out;
  void* out_feat_bf16 = (void*)((u16*)d_out + (size_t)BSZ_*NQ_*DM_);
  void* out_feat_f32  = (void*)((float*)d_out + (size_t)BSZ_*NQ_*DM_);

  // 1. setup: yacc zero + cast0 + detect/prep
  setup_kernel<<<1249, 256, 0, stream>>>(
      features, pos_embed, abuf, queries, query_pos, aq,
      key_proj_w, bkey, query_proj_w, bq,
      A_log, dt_bias, dist_w1, dist_b1, dist_w2, bc_proj_w, dt_proj_w, wprep,
      yacc, flag);

  // 2. kp = abuf @ bkey : (4096 x 1034), K=256
  kp_gemm_kernel<<<dim3(64, 17), 256, 0, stream>>>(abuf, bkey, kp);

  // 3. conv + qproj GEMM
  convqp_kernel<<<4096 + 32, 256, 0, stream>>>(
      flag, kp, key_conv_w, key_conv_b, xact, aq, bq, qproj);

  // 4. dist (standalone, own regalloc)
  dist_kernel<<<BSZ_*LSEQ_/2, 256, 0, stream>>>(flag, anchors, key_pos, kp, xact,
                                                wprep, aw, carr);

  // 5. s1 group-LDS-staged + packed fp32 + b128 reads
  s1m_kernel<<<dim3(8, NCHUNK_, BSZ_*NH_), 256, 0, stream>>>(aw, xact, send, ptot);

  // 6. s2
  s2_kernel<<<1024, 256, 0, stream>>>(qproj, ptot, send, h0buf, hbuf);

  // 7. s3 staged + packed fp32 + b128 reads + cast1
  s3cast_kernel<<<2048 + 512, 256, 0, stream>>>(
      flag, aw, carr, xact, h0buf, yacc,
      out_key_proj_w, bok, out_query_proj_w, boq, ffn_fc1_w, b1w, ffn_fc2_w, b2w);

  // 8. g + lnq
  glnq_kernel<<<4096 + 256, 256, 0, stream>>>(
      flag, yacc, xact, kp, Dvec, key_norm_w, gbuf,
      hbuf, query_norm_w, query_norm_b, lnq);

  // 9. out_feat GEMM + outq GEMM
  ofoq_kernel<<<256 + 16, 256, 0, stream>>>(
      flag, gbuf, bok, out_feat_f32, out_feat_bf16, features,
      lnq, boq, outqf, queries);

  // 10. fc1 + gelu with in-block FFN LN
  fc1g_kernel<<<dim3(4, 16), 256, 0, stream>>>(
      flag, outqf, ffn_norm_w, ffn_norm_b, b1w, ffn_fc1_b, ugbuf);

  // 11. fc2: out_q = outqf + ug @ b2w + b2
  fc2_kernel<<<16, 256, 0, stream>>>(flag, ugbuf, b2w, out_q, outqf, ffn_fc2_b);
}